// Round 1
// baseline (513.728 us; speedup 1.0000x reference)
//
#include <hip/hip_runtime.h>

typedef unsigned short u16;
typedef short bf16x8 __attribute__((ext_vector_type(8)));
typedef float f32x4 __attribute__((ext_vector_type(4)));

// Problem constants: B=4, T=4096, D=1024, N=256, L=768, H=16, dh=64, TE=1024
// I/O dtype: float32 (per reference). Internal MFMA compute: bf16.

__device__ __forceinline__ float b2f(u16 u) {
  union { unsigned int u; float f; } x; x.u = ((unsigned int)u) << 16; return x.f;
}
__device__ __forceinline__ u16 f2b(float f) {
  union { float f; unsigned int u; } x; x.f = f;
  unsigned int u = x.u;
  return (u16)((u + 0x7FFFu + ((u >> 16) & 1u)) >> 16);  // RNE
}

// async global->LDS, 16B per lane. LDS dest = wave-uniform base + lane*16.
#define GLOAD_LDS16(g, l)                                                      \
  __builtin_amdgcn_global_load_lds(                                            \
      (const __attribute__((address_space(1))) unsigned int*)(g),              \
      (__attribute__((address_space(3))) unsigned int*)(l), 16, 0, 0)

// ---------------------------------------------------------------------------
// Fused 4-way transpose + f32->bf16: dst[C][R] = bf16(src[R][C]), C=1024.
// grid (32, 32, 4), block (32,8). z selects {Wq,Wk,Wv,Wo}; R in {1024,768}.
// ---------------------------------------------------------------------------
__global__ __launch_bounds__(256) void transpose4_k(
    const float* __restrict__ Wq, const float* __restrict__ Wk,
    const float* __restrict__ Wv, const float* __restrict__ Wo,
    u16* __restrict__ wqt, u16* __restrict__ wkt,
    u16* __restrict__ wvt, u16* __restrict__ wot) {
  const float* src; u16* dst; int R;
  switch (blockIdx.z) {
    case 0: src = Wq; dst = wqt; R = 1024; break;
    case 1: src = Wk; dst = wkt; R = 768;  break;
    case 2: src = Wv; dst = wvt; R = 768;  break;
    default: src = Wo; dst = wot; R = 1024; break;
  }
  int bx = blockIdx.x * 32, by = blockIdx.y * 32;
  if (by >= R) return;
  __shared__ float t[32][33];
  int x = threadIdx.x, y = threadIdx.y;
#pragma unroll
  for (int i = 0; i < 4; ++i)
    t[y * 4 + i][x] = src[(size_t)(by + y * 4 + i) * 1024 + bx + x];
  __syncthreads();
#pragma unroll
  for (int i = 0; i < 4; ++i)
    dst[(size_t)(bx + y * 4 + i) * R + by + x] = f2b(t[x][y * 4 + i]);
}

// ---------------------------------------------------------------------------
// Row LayerNorm, f32 in -> bf16 out. One block per row. C in {768, 1024}.
// ---------------------------------------------------------------------------
__global__ __launch_bounds__(256) void ln_k(const float* __restrict__ in,
                                            const float* __restrict__ g,
                                            const float* __restrict__ bta,
                                            u16* __restrict__ out, int C) {
  int row = blockIdx.x, tid = threadIdx.x;
  const float* p = in + (size_t)row * C;
  int i0 = tid * 4;
  bool act = i0 < C;
  float v0 = 0.f, v1 = 0.f, v2 = 0.f, v3 = 0.f;
  if (act) {
    float4 u = *(const float4*)(p + i0);
    v0 = u.x; v1 = u.y; v2 = u.z; v3 = u.w;
  }
  float s = v0 + v1 + v2 + v3;
  float q = v0 * v0 + v1 * v1 + v2 * v2 + v3 * v3;
  __shared__ float red[8];
#pragma unroll
  for (int m = 32; m; m >>= 1) { s += __shfl_xor(s, m); q += __shfl_xor(q, m); }
  if ((tid & 63) == 0) { red[tid >> 6] = s; red[4 + (tid >> 6)] = q; }
  __syncthreads();
  s = red[0] + red[1] + red[2] + red[3];
  q = red[4] + red[5] + red[6] + red[7];
  float invC = 1.0f / (float)C;
  float mu = s * invC;
  float rs = rsqrtf(q * invC - mu * mu + 1e-5f);
  if (act) {
    float4 ug = *(const float4*)(g + i0);
    float4 ub = *(const float4*)(bta + i0);
    ushort4 o;
    o.x = f2b((v0 - mu) * rs * ug.x + ub.x);
    o.y = f2b((v1 - mu) * rs * ug.y + ub.y);
    o.z = f2b((v2 - mu) * rs * ug.z + ub.z);
    o.w = f2b((v3 - mu) * rs * ug.w + ub.w);
    *(ushort4*)(out + (size_t)row * C + i0) = o;
  }
}

// ---------------------------------------------------------------------------
// Stylization (in-place safe): out = bf16( silu( LN(y)*(1+scale_b) + shift_b ) ).
// ---------------------------------------------------------------------------
__global__ __launch_bounds__(256) void style_k(const u16* __restrict__ y,
                                               const float* __restrict__ g,
                                               const float* __restrict__ bta,
                                               const float* __restrict__ embo,
                                               u16* __restrict__ out) {
  int row = blockIdx.x, tid = threadIdx.x;
  int b = row >> 12;  // T=4096
  const u16* p = y + (size_t)row * 1024;
  int i0 = tid * 4;
  ushort4 u = *(const ushort4*)(p + i0);
  float v0 = b2f(u.x), v1 = b2f(u.y), v2 = b2f(u.z), v3 = b2f(u.w);
  float s = v0 + v1 + v2 + v3;
  float q = v0 * v0 + v1 * v1 + v2 * v2 + v3 * v3;
  __shared__ float red[8];
#pragma unroll
  for (int m = 32; m; m >>= 1) { s += __shfl_xor(s, m); q += __shfl_xor(q, m); }
  if ((tid & 63) == 0) { red[tid >> 6] = s; red[4 + (tid >> 6)] = q; }
  __syncthreads();
  s = red[0] + red[1] + red[2] + red[3];
  q = red[4] + red[5] + red[6] + red[7];
  const float invC = 1.0f / 1024.0f;
  float mu = s * invC;
  float rs = rsqrtf(q * invC - mu * mu + 1e-5f);
  float4 ug = *(const float4*)(g + i0);
  float4 ub = *(const float4*)(bta + i0);
  float4 sc = *(const float4*)(embo + b * 2048 + i0);
  float4 sh = *(const float4*)(embo + b * 2048 + 1024 + i0);
  float h0 = ((v0 - mu) * rs * ug.x + ub.x) * (1.0f + sc.x) + sh.x;
  float h1 = ((v1 - mu) * rs * ug.y + ub.y) * (1.0f + sc.y) + sh.y;
  float h2 = ((v2 - mu) * rs * ug.z + ub.z) * (1.0f + sc.z) + sh.z;
  float h3 = ((v3 - mu) * rs * ug.w + ub.w) * (1.0f + sc.w) + sh.w;
  ushort4 o;
  o.x = f2b(h0 / (1.0f + __expf(-h0)));
  o.y = f2b(h1 / (1.0f + __expf(-h1)));
  o.z = f2b(h2 / (1.0f + __expf(-h2)));
  o.w = f2b(h3 / (1.0f + __expf(-h3)));
  *(ushort4*)(out + (size_t)row * 1024 + i0) = o;
}

// ---------------------------------------------------------------------------
// emb_out[b][j] = sum_i silu(emb[b][i]) * We[i][j] + be[j], all f32.
// ---------------------------------------------------------------------------
__global__ __launch_bounds__(256) void emb_k(const float* __restrict__ emb,
                                             const float* __restrict__ We,
                                             const float* __restrict__ be,
                                             float* __restrict__ embo) {
  int b = blockIdx.y, tid = threadIdx.x;
  int j = blockIdx.x * 256 + tid;
  __shared__ float se[1024];
  for (int i = tid; i < 1024; i += 256) {
    float v = emb[b * 1024 + i];
    se[i] = v / (1.0f + __expf(-v));
  }
  __syncthreads();
  float acc = 0.f;
#pragma unroll 8
  for (int i = 0; i < 1024; ++i) acc += se[i] * We[(size_t)i * 2048 + j];
  embo[b * 2048 + j] = acc + be[j];
}

// ---------------------------------------------------------------------------
// GEMM  C[M][Nn] = A[M][K] @ Bt[Nn][K]^T + bias(f32), A/Bt bf16.
// 128x128 tile, m97 structure. Kept for the small K/V projections
// (M=1024: needs the finer grid for CU coverage).
// mode 0: Cb[row*Nn+col] (bf16)
// mode 1: V-transpose store: Cb[((row>>8)*1024 + col)*256 + (row&255)] (bf16)
// mode 2: Cf[row*Nn+col] = acc + bias + res[row*Nn+col]  (f32 out, f32 res)
// ---------------------------------------------------------------------------
__global__ __launch_bounds__(256) void gemm_bt_k(const u16* __restrict__ A,
                                                 const u16* __restrict__ Bt,
                                                 const float* __restrict__ bias,
                                                 const float* __restrict__ res,
                                                 u16* __restrict__ Cb,
                                                 float* __restrict__ Cf,
                                                 int M, int Nn, int K, int mode) {
  __shared__ __align__(16) short As[128 * 64];
  __shared__ __align__(16) short Bs[128 * 64];
  int tid = threadIdx.x;
  int m0 = blockIdx.x * 128, n0 = blockIdx.y * 128;  // rows on x (XCD swizzle)
  int wave = tid >> 6, lane = tid & 63;
  int l16 = lane & 15, quad = lane >> 4;
  int wm = (wave >> 1) * 64, wn = (wave & 1) * 64;

  f32x4 acc[4][4];
#pragma unroll
  for (int i = 0; i < 4; ++i)
#pragma unroll
    for (int j = 0; j < 4; ++j)
#pragma unroll
      for (int r = 0; r < 4; ++r) acc[i][j][r] = 0.f;

  for (int kt = 0; kt < K; kt += 64) {
#pragma unroll
    for (int p = 0; p < 4; ++p) {
      int c = p * 256 + tid;
      int r = c >> 3;
      int cd = ((c & 7) ^ (r & 7)) * 8;   // swizzled global column (shorts)
      int lb = (p * 256 + wave * 64) * 8; // wave's LDS chunk base (shorts)
      GLOAD_LDS16(A + (size_t)(m0 + r) * K + kt + cd, As + lb);
      GLOAD_LDS16(Bt + (size_t)(n0 + r) * K + kt + cd, Bs + lb);
    }
    __syncthreads();
#pragma unroll
    for (int ks = 0; ks < 2; ++ks) {
      int swz = ((ks * 4 + quad) ^ (l16 & 7)) * 8;
      bf16x8 af[4], bfr[4];
#pragma unroll
      for (int i = 0; i < 4; ++i)
        af[i] = *(const bf16x8*)&As[(wm + i * 16 + l16) * 64 + swz];
#pragma unroll
      for (int j = 0; j < 4; ++j)
        bfr[j] = *(const bf16x8*)&Bs[(wn + j * 16 + l16) * 64 + swz];
#pragma unroll
      for (int i = 0; i < 4; ++i)
#pragma unroll
        for (int j = 0; j < 4; ++j)
          acc[i][j] = __builtin_amdgcn_mfma_f32_16x16x32_bf16(af[i], bfr[j], acc[i][j], 0, 0, 0);
    }
    __syncthreads();
  }

#pragma unroll
  for (int j = 0; j < 4; ++j) {
    int col = n0 + wn + j * 16 + l16;
    float bv = bias[col];
#pragma unroll
    for (int i = 0; i < 4; ++i) {
      int row0 = m0 + wm + i * 16 + quad * 4;
#pragma unroll
      for (int r = 0; r < 4; ++r) {
        int row = row0 + r;
        float v = acc[i][j][r] + bv;
        if (mode == 2) {
          Cf[(size_t)row * Nn + col] = v + res[(size_t)row * Nn + col];
        } else if (mode == 1) {
          Cb[((size_t)((row >> 8) * 1024 + col)) * 256 + (row & 255)] = f2b(v);
        } else {
          Cb[(size_t)row * Nn + col] = f2b(v);
        }
      }
    }
  }
}

// ---------------------------------------------------------------------------
// 256x256-tile phased GEMM (8-phase/T3+T4+T2+T5 port) for the two big
// 16384x1024x1024 GEMMs.  8 waves (2M x 4N), per-wave output 128x64,
// BK=64, double-buffered 128 KiB LDS.  Per K-tile: 4 phases, each =
// {issue next-tile global_load_lds || ds_read one C-quadrant's frags;
//  s_barrier; setprio(1); 16 MFMA; setprio(0); s_barrier}.
// Raw s_barrier (NOT __syncthreads) keeps prefetch loads in flight across
// barriers; one vmcnt(0) per K-tile boundary, with the next tile's last
// half staged 2 phases earlier so the wait is mostly covered.
// Same XOR-chunk bank swizzle as gemm_bt_k (proven 0-conflict): LDS slot
// (r, cd) holds global chunk (r, cd ^ (r&7)); reads xor back.
// grid (M/256, Nn/256) = (64,4) -> exactly 1 block/CU (all co-resident).
// mode 0: Cb = bf16(acc+bias);  mode 2: Cf = acc+bias+res (f32).
// ---------------------------------------------------------------------------
__global__ __launch_bounds__(512, 2) void gemm256_k(const u16* __restrict__ A,
                                                    const u16* __restrict__ Bt,
                                                    const float* __restrict__ bias,
                                                    const float* __restrict__ res,
                                                    u16* __restrict__ Cb,
                                                    float* __restrict__ Cf,
                                                    int M, int Nn, int K, int mode) {
  __shared__ __align__(16) short As[2][256 * 64];
  __shared__ __align__(16) short Bs[2][256 * 64];
  int tid = threadIdx.x;
  int m0 = blockIdx.x * 256, n0 = blockIdx.y * 256;
  int wave = tid >> 6, lane = tid & 63;
  int l16 = lane & 15, quad = lane >> 4;
  int wm = (wave >> 2) * 128;  // 2 row-waves
  int wn = (wave & 3) * 64;    // 4 col-waves
  const u16* Ag = A + (size_t)m0 * K;
  const u16* Bg = Bt + (size_t)n0 * K;

  f32x4 acc[8][4];
#pragma unroll
  for (int i = 0; i < 8; ++i)
#pragma unroll
    for (int j = 0; j < 4; ++j)
#pragma unroll
      for (int r = 0; r < 4; ++r) acc[i][j][r] = 0.f;

  // Stage one quarter (512 chunks = 64 rows) of a 256x64 operand tile.
  // Chunk c -> LDS slot (r=c>>3, c&7) <- global chunk (r, (c&7)^(r&7)).
#define ST1(gb, lb, p, kofs)                                                   \
  do {                                                                         \
    int c_ = (p) * 512 + tid;                                                  \
    int r_ = c_ >> 3;                                                          \
    int cd_ = ((c_ & 7) ^ (r_ & 7)) * 8;                                       \
    GLOAD_LDS16((gb) + (size_t)r_ * K + (kofs) + cd_,                          \
                (lb) + ((p) * 512 + (wave << 6)) * 8);                         \
  } while (0)

  // prologue: stage tile 0 fully, drain, publish.
  ST1(Ag, &As[0][0], 0, 0); ST1(Ag, &As[0][0], 1, 0);
  ST1(Ag, &As[0][0], 2, 0); ST1(Ag, &As[0][0], 3, 0);
  ST1(Bg, &Bs[0][0], 0, 0); ST1(Bg, &Bs[0][0], 1, 0);
  ST1(Bg, &Bs[0][0], 2, 0); ST1(Bg, &Bs[0][0], 3, 0);
  asm volatile("s_waitcnt vmcnt(0)" ::: "memory");
  __builtin_amdgcn_s_barrier();

  int cur = 0;
  for (int kt = 0; kt < K; kt += 64) {
    int ktn = kt + 64;
    bool hn = ktn < K;
    short* as = &As[cur][0];
    short* bs = &Bs[cur][0];
    short* an = &As[cur ^ 1][0];
    short* bn = &Bs[cur ^ 1][0];
    bf16x8 af[4][2], bfj[2][2];

    // ---- phase 0: quadrant (qm=0, qn=0) ---------------------------------
    if (hn) { ST1(Ag, an, 0, ktn); ST1(Ag, an, 1, ktn); ST1(Bg, bn, 0, ktn); }
#pragma unroll
    for (int mi = 0; mi < 4; ++mi)
#pragma unroll
      for (int ks = 0; ks < 2; ++ks)
        af[mi][ks] = *(const bf16x8*)&as[(wm + mi * 16 + l16) * 64 +
                                         (((ks * 4 + quad) ^ (l16 & 7)) * 8)];
#pragma unroll
    for (int ni = 0; ni < 2; ++ni)
#pragma unroll
      for (int ks = 0; ks < 2; ++ks)
        bfj[ni][ks] = *(const bf16x8*)&bs[(wn + ni * 16 + l16) * 64 +
                                          (((ks * 4 + quad) ^ (l16 & 7)) * 8)];
    __builtin_amdgcn_s_barrier();
    __builtin_amdgcn_s_setprio(1);
#pragma unroll
    for (int ks = 0; ks < 2; ++ks)
#pragma unroll
      for (int mi = 0; mi < 4; ++mi)
#pragma unroll
        for (int ni = 0; ni < 2; ++ni)
          acc[mi][ni] = __builtin_amdgcn_mfma_f32_16x16x32_bf16(
              af[mi][ks], bfj[ni][ks], acc[mi][ni], 0, 0, 0);
    __builtin_amdgcn_s_setprio(0);
    __builtin_amdgcn_s_barrier();

    // ---- phase 1: quadrant (qm=0, qn=1) — af reused ---------------------
    if (hn) { ST1(Ag, an, 2, ktn); ST1(Ag, an, 3, ktn); ST1(Bg, bn, 1, ktn); }
#pragma unroll
    for (int ni = 0; ni < 2; ++ni)
#pragma unroll
      for (int ks = 0; ks < 2; ++ks)
        bfj[ni][ks] = *(const bf16x8*)&bs[(wn + (ni + 2) * 16 + l16) * 64 +
                                          (((ks * 4 + quad) ^ (l16 & 7)) * 8)];
    __builtin_amdgcn_s_barrier();
    __builtin_amdgcn_s_setprio(1);
#pragma unroll
    for (int ks = 0; ks < 2; ++ks)
#pragma unroll
      for (int mi = 0; mi < 4; ++mi)
#pragma unroll
        for (int ni = 0; ni < 2; ++ni)
          acc[mi][ni + 2] = __builtin_amdgcn_mfma_f32_16x16x32_bf16(
              af[mi][ks], bfj[ni][ks], acc[mi][ni + 2], 0, 0, 0);
    __builtin_amdgcn_s_setprio(0);
    __builtin_amdgcn_s_barrier();

    // ---- phase 2: quadrant (qm=1, qn=0) ---------------------------------
    if (hn) { ST1(Bg, bn, 2, ktn); ST1(Bg, bn, 3, ktn); }
#pragma unroll
    for (int mi = 0; mi < 4; ++mi)
#pragma unroll
      for (int ks = 0; ks < 2; ++ks)
        af[mi][ks] = *(const bf16x8*)&as[(wm + (mi + 4) * 16 + l16) * 64 +
                                         (((ks * 4 + quad) ^ (l16 & 7)) * 8)];
#pragma unroll
    for (int ni = 0; ni < 2; ++ni)
#pragma unroll
      for (int ks = 0; ks < 2; ++ks)
        bfj[ni][ks] = *(const bf16x8*)&bs[(wn + ni * 16 + l16) * 64 +
                                          (((ks * 4 + quad) ^ (l16 & 7)) * 8)];
    __builtin_amdgcn_s_barrier();
    __builtin_amdgcn_s_setprio(1);
#pragma unroll
    for (int ks = 0; ks < 2; ++ks)
#pragma unroll
      for (int mi = 0; mi < 4; ++mi)
#pragma unroll
        for (int ni = 0; ni < 2; ++ni)
          acc[mi + 4][ni] = __builtin_amdgcn_mfma_f32_16x16x32_bf16(
              af[mi][ks], bfj[ni][ks], acc[mi + 4][ni], 0, 0, 0);
    __builtin_amdgcn_s_setprio(0);
    __builtin_amdgcn_s_barrier();

    // ---- phase 3: quadrant (qm=1, qn=1) — af reused ---------------------
#pragma unroll
    for (int ni = 0; ni < 2; ++ni)
#pragma unroll
      for (int ks = 0; ks < 2; ++ks)
        bfj[ni][ks] = *(const bf16x8*)&bs[(wn + (ni + 2) * 16 + l16) * 64 +
                                          (((ks * 4 + quad) ^ (l16 & 7)) * 8)];
    __builtin_amdgcn_s_barrier();
    __builtin_amdgcn_s_setprio(1);
#pragma unroll
    for (int ks = 0; ks < 2; ++ks)
#pragma unroll
      for (int mi = 0; mi < 4; ++mi)
#pragma unroll
        for (int ni = 0; ni < 2; ++ni)
          acc[mi + 4][ni + 2] = __builtin_amdgcn_mfma_f32_16x16x32_bf16(
              af[mi][ks], bfj[ni][ks], acc[mi + 4][ni + 2], 0, 0, 0);
    __builtin_amdgcn_s_setprio(0);
    __builtin_amdgcn_s_barrier();

    // ---- K-tile boundary: next tile's loads must have landed ------------
    if (hn) {
      asm volatile("s_waitcnt vmcnt(0)" ::: "memory");
      __builtin_amdgcn_s_barrier();
    }
    cur ^= 1;
  }
#undef ST1

  // epilogue
#pragma unroll
  for (int ni = 0; ni < 4; ++ni) {
    int col = n0 + wn + ni * 16 + l16;
    float bv = bias[col];
#pragma unroll
    for (int mi = 0; mi < 8; ++mi) {
      int row0 = m0 + wm + mi * 16 + quad * 4;
#pragma unroll
      for (int r = 0; r < 4; ++r) {
        int row = row0 + r;
        float v = acc[mi][ni][r] + bv;
        if (mode == 2) {
          Cf[(size_t)row * Nn + col] = v + res[(size_t)row * Nn + col];
        } else {
          Cb[(size_t)row * Nn + col] = f2b(v);
        }
      }
    }
  }
}

// ---------------------------------------------------------------------------
// Cross-attention: per (b,h), 64 Q-rows per block (4 waves x 16 rows).
// All operands bf16, accum f32. LDS = exactly 64 KB.
// ---------------------------------------------------------------------------
__global__ __launch_bounds__(256) void attn_k(const u16* __restrict__ Q,
                                              const u16* __restrict__ Kt,
                                              const u16* __restrict__ VT,
                                              u16* __restrict__ Y) {
  __shared__ __align__(16) short KsPs[256 * 64];  // K tile; reused as P (64x256)
  __shared__ __align__(16) short Vt[64 * 256];    // V^T tile: [d][token]
  int tid = threadIdx.x;
  int t0 = blockIdx.x * 64, h = blockIdx.y, b = blockIdx.z;
  int wave = tid >> 6, lane = tid & 63;
  int l16 = lane & 15, quad = lane >> 4;
  int wb = wave * 16;

#pragma unroll
  for (int p = 0; p < 8; ++p) {
    int c = tid + p * 256;
    int n = c >> 3, cd = c & 7;
    *(int4*)&KsPs[n * 64 + ((cd ^ (n & 7)) * 8)] =
        *(const int4*)(Kt + ((size_t)(b * 256 + n)) * 1024 + h * 64 + cd * 8);
  }
#pragma unroll
  for (int p = 0; p < 8; ++p) {
    int c = tid + p * 256;
    int d = c >> 5, ch = c & 31;
    *(int4*)&Vt[d * 256 + ((ch ^ (d & 7)) * 8)] =
        *(const int4*)(VT + ((size_t)(b * 1024 + h * 64 + d)) * 256 + ch * 8);
  }
  const u16* qrow = Q + ((size_t)(b * 4096 + t0 + wb + l16)) * 1024 + h * 64;
  bf16x8 qf0 = *(const bf16x8*)(qrow + quad * 8);
  bf16x8 qf1 = *(const bf16x8*)(qrow + 32 + quad * 8);
  __syncthreads();

  f32x4 sa[16];
#pragma unroll
  for (int nt = 0; nt < 16; ++nt)
#pragma unroll
    for (int r = 0; r < 4; ++r) sa[nt][r] = 0.f;
#pragma unroll
  for (int ks = 0; ks < 2; ++ks) {
    bf16x8 af = ks ? qf1 : qf0;
#pragma unroll
    for (int nt = 0; nt < 16; ++nt) {
      int n = nt * 16 + l16;
      bf16x8 bfr = *(const bf16x8*)&KsPs[n * 64 + (((ks * 4 + quad) ^ (n & 7)) * 8)];
      sa[nt] = __builtin_amdgcn_mfma_f32_16x16x32_bf16(af, bfr, sa[nt], 0, 0, 0);
    }
  }
  __syncthreads();  // all waves done reading K before P overwrites it

#pragma unroll
  for (int r = 0; r < 4; ++r) {
    float mx = -3.0e38f;
#pragma unroll
    for (int nt = 0; nt < 16; ++nt) mx = fmaxf(mx, sa[nt][r]);
    mx = fmaxf(mx, __shfl_xor(mx, 1));
    mx = fmaxf(mx, __shfl_xor(mx, 2));
    mx = fmaxf(mx, __shfl_xor(mx, 4));
    mx = fmaxf(mx, __shfl_xor(mx, 8));
    float e[16];
    float sum = 0.f;
#pragma unroll
    for (int nt = 0; nt < 16; ++nt) {
      e[nt] = __expf((sa[nt][r] - mx) * 0.125f);
      sum += e[nt];
    }
    sum += __shfl_xor(sum, 1);
    sum += __shfl_xor(sum, 2);
    sum += __shfl_xor(sum, 4);
    sum += __shfl_xor(sum, 8);
    float rsc = 1.0f / sum;
    int prow = wb + quad * 4 + r;
#pragma unroll
    for (int nt = 0; nt < 16; ++nt) {
      int col = nt * 16 + l16;
      KsPs[prow * 256 + (((col >> 3) ^ (prow & 7)) * 8) + (col & 7)] =
          (short)f2b(e[nt] * rsc);
    }
  }
  __syncthreads();

  f32x4 ya[4];
#pragma unroll
  for (int j = 0; j < 4; ++j)
#pragma unroll
    for (int r = 0; r < 4; ++r) ya[j][r] = 0.f;
  int m = wb + l16;
#pragma unroll
  for (int kk = 0; kk < 8; ++kk) {
    bf16x8 af = *(const bf16x8*)&KsPs[m * 256 + (((kk * 4 + quad) ^ (m & 7)) * 8)];
#pragma unroll
    for (int j = 0; j < 4; ++j) {
      int d = j * 16 + l16;
      bf16x8 bfr = *(const bf16x8*)&Vt[d * 256 + (((kk * 4 + quad) ^ (d & 7)) * 8)];
      ya[j] = __builtin_amdgcn_mfma_f32_16x16x32_bf16(af, bfr, ya[j], 0, 0, 0);
    }
  }
#pragma unroll
  for (int j = 0; j < 4; ++j)
#pragma unroll
    for (int r = 0; r < 4; ++r)
      Y[((size_t)(b * 4096 + t0 + wb + quad * 4 + r)) * 1024 + h * 64 + j * 16 + l16] =
          f2b(ya[j][r]);
}

// ---------------------------------------------------------------------------
extern "C" void kernel_launch(void* const* d_in, const int* in_sizes, int n_in,
                              void* d_out, int out_size, void* d_ws, size_t ws_size,
                              hipStream_t stream) {
  const float* x       = (const float*)d_in[0];
  const float* xf      = (const float*)d_in[1];
  const float* emb     = (const float*)d_in[2];
  const float* norm_g  = (const float*)d_in[3];
  const float* norm_b  = (const float*)d_in[4];
  const float* tnorm_g = (const float*)d_in[5];
  const float* tnorm_b = (const float*)d_in[6];
  const float* Wq      = (const float*)d_in[7];
  const float* bq      = (const float*)d_in[8];
  const float* Wk      = (const float*)d_in[9];
  const float* bk      = (const float*)d_in[10];
  const float* Wv      = (const float*)d_in[11];
  const float* bv      = (const float*)d_in[12];
  const float* We      = (const float*)d_in[13];
  const float* be      = (const float*)d_in[14];
  const float* snorm_g = (const float*)d_in[15];
  const float* snorm_b = (const float*)d_in[16];
  const float* Wo      = (const float*)d_in[17];
  const float* bo      = (const float*)d_in[18];

  const size_t MB = 1024 * 1024;
  // d_out (64 MB f32) hosts transient bf16 buffers that die before the final
  // full-d_out write: Q (32 MB) + Wq^T/Wk^T/Wv^T transposed weights.
  char* dout = (char*)d_out;
  u16* qbuf = (u16*)(dout);             // 32 MB bf16 Q (dead after attn)
  u16* wqt  = (u16*)(dout + 32 * MB);   // 2 MB   (dead after Q-GEMM)
  u16* wkt  = (u16*)(dout + 34 * MB);   // 1.5 MB (dead after K-GEMM)
  u16* wvt  = (u16*)(dout + 36 * MB);   // 1.5 MB (dead after V-GEMM)
  float* out = (float*)d_out;

  // Workspace: ~39.6 MB total.
  char* ws = (char*)d_ws;
  u16* big1 = (u16*)(ws);                        // 32 MB: LN(x) -> y -> s
  u16* xfn  = (u16*)(ws + 32 * MB);              // 1.5 MB
  u16* kws  = (u16*)(ws + 33 * MB + 512 * 1024); // 2 MB  (B,256,1024)
  u16* vtws = (u16*)(ws + 35 * MB + 512 * 1024); // 2 MB  (B,1024,256)
  u16* wot  = (u16*)(ws + 37 * MB + 512 * 1024); // 2 MB  (needed during final GEMM)
  float* embo = (float*)(ws + 39 * MB + 512 * 1024); // 32 KB f32

  // weight transposes (f32 -> bf16, B-operand wants k-contiguous), one launch
  transpose4_k<<<dim3(32, 32, 4), dim3(32, 8), 0, stream>>>(
      Wq, Wk, Wv, Wo, wqt, wkt, wvt, wot);

  // layernorms (f32 -> bf16)
  ln_k<<<16384, 256, 0, stream>>>(x, norm_g, norm_b, big1, 1024);
  ln_k<<<1024, 256, 0, stream>>>(xf, tnorm_g, tnorm_b, xfn, 768);

  // projections: Q (big, 256^2 phased) -> d_out; K -> kws; V -> vtws (transposed)
  gemm256_k<<<dim3(64, 4), 512, 0, stream>>>(big1, wqt, bq, nullptr, qbuf, nullptr, 16384, 1024, 1024, 0);
  gemm_bt_k<<<dim3(8, 8), 256, 0, stream>>>(xfn, wkt, bk, nullptr, kws, nullptr, 1024, 1024, 768, 0);
  gemm_bt_k<<<dim3(8, 8), 256, 0, stream>>>(xfn, wvt, bv, nullptr, vtws, nullptr, 1024, 1024, 768, 1);

  // emb -> scale/shift (f32)
  emb_k<<<dim3(8, 4), 256, 0, stream>>>(emb, We, be, embo);

  // attention: reads Q (=d_out lower half), writes y (bf16) -> big1
  attn_k<<<dim3(64, 16, 4), 256, 0, stream>>>(qbuf, kws, vtws, big1);

  // stylization in-place: big1 (y) -> big1 (s)
  style_k<<<16384, 256, 0, stream>>>(big1, snorm_g, snorm_b, embo, big1);

  // out projection + bias + residual(x, f32) -> d_out (f32, full overwrite)
  gemm256_k<<<dim3(64, 4), 512, 0, stream>>>(big1, wot, bo, x, nullptr, out, 16384, 1024, 1024, 2);
}

// Round 3
// 477.538 us; speedup vs baseline: 1.0758x; 1.0758x over previous
//
#include <hip/hip_runtime.h>

typedef unsigned short u16;
typedef short bf16x8 __attribute__((ext_vector_type(8)));
typedef float f32x4 __attribute__((ext_vector_type(4)));

// Problem constants: B=4, T=4096, D=1024, N=256, L=768, H=16, dh=64, TE=1024
// I/O dtype: float32 (per reference). Internal MFMA compute: bf16.

__device__ __forceinline__ float b2f(u16 u) {
  union { unsigned int u; float f; } x; x.u = ((unsigned int)u) << 16; return x.f;
}
__device__ __forceinline__ u16 f2b(float f) {
  union { float f; unsigned int u; } x; x.f = f;
  unsigned int u = x.u;
  return (u16)((u + 0x7FFFu + ((u >> 16) & 1u)) >> 16);  // RNE
}

// async global->LDS, 16B per lane. LDS dest = wave-uniform base + lane*16.
#define GLOAD_LDS16(g, l)                                                      \
  __builtin_amdgcn_global_load_lds(                                            \
      (const __attribute__((address_space(1))) unsigned int*)(g),              \
      (__attribute__((address_space(3))) unsigned int*)(l), 16, 0, 0)

// ---------------------------------------------------------------------------
// Fused 4-way transpose + f32->bf16: dst[C][R] = bf16(src[R][C]), C=1024.
// grid (32, 32, 4), block (32,8). z selects {Wq,Wk,Wv,Wo}; R in {1024,768}.
// ---------------------------------------------------------------------------
__global__ __launch_bounds__(256) void transpose4_k(
    const float* __restrict__ Wq, const float* __restrict__ Wk,
    const float* __restrict__ Wv, const float* __restrict__ Wo,
    u16* __restrict__ wqt, u16* __restrict__ wkt,
    u16* __restrict__ wvt, u16* __restrict__ wot) {
  const float* src; u16* dst; int R;
  switch (blockIdx.z) {
    case 0: src = Wq; dst = wqt; R = 1024; break;
    case 1: src = Wk; dst = wkt; R = 768;  break;
    case 2: src = Wv; dst = wvt; R = 768;  break;
    default: src = Wo; dst = wot; R = 1024; break;
  }
  int bx = blockIdx.x * 32, by = blockIdx.y * 32;
  if (by >= R) return;
  __shared__ float t[32][33];
  int x = threadIdx.x, y = threadIdx.y;
#pragma unroll
  for (int i = 0; i < 4; ++i)
    t[y * 4 + i][x] = src[(size_t)(by + y * 4 + i) * 1024 + bx + x];
  __syncthreads();
#pragma unroll
  for (int i = 0; i < 4; ++i)
    dst[(size_t)(bx + y * 4 + i) * R + by + x] = f2b(t[x][y * 4 + i]);
}

// ---------------------------------------------------------------------------
// Row LayerNorm, f32 in -> bf16 out. One block per row. C in {768, 1024}.
// ---------------------------------------------------------------------------
__global__ __launch_bounds__(256) void ln_k(const float* __restrict__ in,
                                            const float* __restrict__ g,
                                            const float* __restrict__ bta,
                                            u16* __restrict__ out, int C) {
  int row = blockIdx.x, tid = threadIdx.x;
  const float* p = in + (size_t)row * C;
  int i0 = tid * 4;
  bool act = i0 < C;
  float v0 = 0.f, v1 = 0.f, v2 = 0.f, v3 = 0.f;
  if (act) {
    float4 u = *(const float4*)(p + i0);
    v0 = u.x; v1 = u.y; v2 = u.z; v3 = u.w;
  }
  float s = v0 + v1 + v2 + v3;
  float q = v0 * v0 + v1 * v1 + v2 * v2 + v3 * v3;
  __shared__ float red[8];
#pragma unroll
  for (int m = 32; m; m >>= 1) { s += __shfl_xor(s, m); q += __shfl_xor(q, m); }
  if ((tid & 63) == 0) { red[tid >> 6] = s; red[4 + (tid >> 6)] = q; }
  __syncthreads();
  s = red[0] + red[1] + red[2] + red[3];
  q = red[4] + red[5] + red[6] + red[7];
  float invC = 1.0f / (float)C;
  float mu = s * invC;
  float rs = rsqrtf(q * invC - mu * mu + 1e-5f);
  if (act) {
    float4 ug = *(const float4*)(g + i0);
    float4 ub = *(const float4*)(bta + i0);
    ushort4 o;
    o.x = f2b((v0 - mu) * rs * ug.x + ub.x);
    o.y = f2b((v1 - mu) * rs * ug.y + ub.y);
    o.z = f2b((v2 - mu) * rs * ug.z + ub.z);
    o.w = f2b((v3 - mu) * rs * ug.w + ub.w);
    *(ushort4*)(out + (size_t)row * C + i0) = o;
  }
}

// ---------------------------------------------------------------------------
// Stylization (in-place safe): out = bf16( silu( LN(y)*(1+scale_b) + shift_b ) ).
// ---------------------------------------------------------------------------
__global__ __launch_bounds__(256) void style_k(const u16* __restrict__ y,
                                               const float* __restrict__ g,
                                               const float* __restrict__ bta,
                                               const float* __restrict__ embo,
                                               u16* __restrict__ out) {
  int row = blockIdx.x, tid = threadIdx.x;
  int b = row >> 12;  // T=4096
  const u16* p = y + (size_t)row * 1024;
  int i0 = tid * 4;
  ushort4 u = *(const ushort4*)(p + i0);
  float v0 = b2f(u.x), v1 = b2f(u.y), v2 = b2f(u.z), v3 = b2f(u.w);
  float s = v0 + v1 + v2 + v3;
  float q = v0 * v0 + v1 * v1 + v2 * v2 + v3 * v3;
  __shared__ float red[8];
#pragma unroll
  for (int m = 32; m; m >>= 1) { s += __shfl_xor(s, m); q += __shfl_xor(q, m); }
  if ((tid & 63) == 0) { red[tid >> 6] = s; red[4 + (tid >> 6)] = q; }
  __syncthreads();
  s = red[0] + red[1] + red[2] + red[3];
  q = red[4] + red[5] + red[6] + red[7];
  const float invC = 1.0f / 1024.0f;
  float mu = s * invC;
  float rs = rsqrtf(q * invC - mu * mu + 1e-5f);
  float4 ug = *(const float4*)(g + i0);
  float4 ub = *(const float4*)(bta + i0);
  float4 sc = *(const float4*)(embo + b * 2048 + i0);
  float4 sh = *(const float4*)(embo + b * 2048 + 1024 + i0);
  float h0 = ((v0 - mu) * rs * ug.x + ub.x) * (1.0f + sc.x) + sh.x;
  float h1 = ((v1 - mu) * rs * ug.y + ub.y) * (1.0f + sc.y) + sh.y;
  float h2 = ((v2 - mu) * rs * ug.z + ub.z) * (1.0f + sc.z) + sh.z;
  float h3 = ((v3 - mu) * rs * ug.w + ub.w) * (1.0f + sc.w) + sh.w;
  ushort4 o;
  o.x = f2b(h0 / (1.0f + __expf(-h0)));
  o.y = f2b(h1 / (1.0f + __expf(-h1)));
  o.z = f2b(h2 / (1.0f + __expf(-h2)));
  o.w = f2b(h3 / (1.0f + __expf(-h3)));
  *(ushort4*)(out + (size_t)row * 1024 + i0) = o;
}

// ---------------------------------------------------------------------------
// emb_out[b][j] = sum_i silu(emb[b][i]) * We[i][j] + be[j], all f32.
// ---------------------------------------------------------------------------
__global__ __launch_bounds__(256) void emb_k(const float* __restrict__ emb,
                                             const float* __restrict__ We,
                                             const float* __restrict__ be,
                                             float* __restrict__ embo) {
  int b = blockIdx.y, tid = threadIdx.x;
  int j = blockIdx.x * 256 + tid;
  __shared__ float se[1024];
  for (int i = tid; i < 1024; i += 256) {
    float v = emb[b * 1024 + i];
    se[i] = v / (1.0f + __expf(-v));
  }
  __syncthreads();
  float acc = 0.f;
#pragma unroll 8
  for (int i = 0; i < 1024; ++i) acc += se[i] * We[(size_t)i * 2048 + j];
  embo[b * 2048 + j] = acc + be[j];
}

// ---------------------------------------------------------------------------
// GEMM  C[M][Nn] = A[M][K] @ Bt[Nn][K]^T + bias(f32), A/Bt bf16.
// 128x128 tile, m97 structure. Kept for the small K/V projections
// (M=1024: needs the finer grid for CU coverage).
// mode 0: Cb[row*Nn+col] (bf16)
// mode 1: V-transpose store: Cb[((row>>8)*1024 + col)*256 + (row&255)] (bf16)
// mode 2: Cf[row*Nn+col] = acc + bias + res[row*Nn+col]  (f32 out, f32 res)
// ---------------------------------------------------------------------------
__global__ __launch_bounds__(256) void gemm_bt_k(const u16* __restrict__ A,
                                                 const u16* __restrict__ Bt,
                                                 const float* __restrict__ bias,
                                                 const float* __restrict__ res,
                                                 u16* __restrict__ Cb,
                                                 float* __restrict__ Cf,
                                                 int M, int Nn, int K, int mode) {
  __shared__ __align__(16) short As[128 * 64];
  __shared__ __align__(16) short Bs[128 * 64];
  int tid = threadIdx.x;
  int m0 = blockIdx.x * 128, n0 = blockIdx.y * 128;
  int wave = tid >> 6, lane = tid & 63;
  int l16 = lane & 15, quad = lane >> 4;
  int wm = (wave >> 1) * 64, wn = (wave & 1) * 64;

  f32x4 acc[4][4];
#pragma unroll
  for (int i = 0; i < 4; ++i)
#pragma unroll
    for (int j = 0; j < 4; ++j)
#pragma unroll
      for (int r = 0; r < 4; ++r) acc[i][j][r] = 0.f;

  for (int kt = 0; kt < K; kt += 64) {
#pragma unroll
    for (int p = 0; p < 4; ++p) {
      int c = p * 256 + tid;
      int r = c >> 3;
      int cd = ((c & 7) ^ (r & 7)) * 8;   // swizzled global column (shorts)
      int lb = (p * 256 + wave * 64) * 8; // wave's LDS chunk base (shorts)
      GLOAD_LDS16(A + (size_t)(m0 + r) * K + kt + cd, As + lb);
      GLOAD_LDS16(Bt + (size_t)(n0 + r) * K + kt + cd, Bs + lb);
    }
    __syncthreads();
#pragma unroll
    for (int ks = 0; ks < 2; ++ks) {
      int swz = ((ks * 4 + quad) ^ (l16 & 7)) * 8;
      bf16x8 af[4], bfr[4];
#pragma unroll
      for (int i = 0; i < 4; ++i)
        af[i] = *(const bf16x8*)&As[(wm + i * 16 + l16) * 64 + swz];
#pragma unroll
      for (int j = 0; j < 4; ++j)
        bfr[j] = *(const bf16x8*)&Bs[(wn + j * 16 + l16) * 64 + swz];
#pragma unroll
      for (int i = 0; i < 4; ++i)
#pragma unroll
        for (int j = 0; j < 4; ++j)
          acc[i][j] = __builtin_amdgcn_mfma_f32_16x16x32_bf16(af[i], bfr[j], acc[i][j], 0, 0, 0);
    }
    __syncthreads();
  }

#pragma unroll
  for (int j = 0; j < 4; ++j) {
    int col = n0 + wn + j * 16 + l16;
    float bv = bias[col];
#pragma unroll
    for (int i = 0; i < 4; ++i) {
      int row0 = m0 + wm + i * 16 + quad * 4;
#pragma unroll
      for (int r = 0; r < 4; ++r) {
        int row = row0 + r;
        float v = acc[i][j][r] + bv;
        if (mode == 2) {
          Cf[(size_t)row * Nn + col] = v + res[(size_t)row * Nn + col];
        } else if (mode == 1) {
          Cb[((size_t)((row >> 8) * 1024 + col)) * 256 + (row & 255)] = f2b(v);
        } else {
          Cb[(size_t)row * Nn + col] = f2b(v);
        }
      }
    }
  }
}

// ---------------------------------------------------------------------------
// 256x256-tile deep-pipelined GEMM for the two big 16384x1024x1024 GEMMs.
// BK=32, QUADRUPLE-buffered LDS (4 x 16KB x 2 operands = 128 KiB), 8 waves
// (2M x 4N), per-wave output 128x64 (acc[8][4]).
// Per K-tile (exactly 4 global_load_lds per wave):
//   s_waitcnt vmcnt(8)   <- tile t landed; tiles t+1,t+2 (8 loads) in flight
//   s_barrier            <- all waves' slices of tile t visible
//   stage tile t+3       <- overwrites buf[(t-1)&3]; its readers finished
//                           before this barrier (reads consumed pre-barrier)
//   12 ds_read_b128 + 32 MFMA (setprio 1)
// Counted vmcnt never reaches 0 in the main loop (T4); prefetch depth = 3
// K-tiles; ONE barrier per tile.
// Bank swizzle (BK=32, 4 chunks/row): slot = q ^ ((row>>1)&3); global source
// pre-swizzled so LDS dest stays linear (gload_lds HW constraint).
// grid (M/256, Nn/256) = (64,4) -> 1 block/CU, all co-resident.
// mode 0: Cb = bf16(acc+bias);  mode 2: Cf = acc+bias+res (f32).
// ---------------------------------------------------------------------------
__global__ __launch_bounds__(512, 2) void gemm256_k(const u16* __restrict__ A,
                                                    const u16* __restrict__ Bt,
                                                    const float* __restrict__ bias,
                                                    const float* __restrict__ res,
                                                    u16* __restrict__ Cb,
                                                    float* __restrict__ Cf,
                                                    int M, int Nn, int K, int mode) {
  __shared__ __align__(16) short As[4][256 * 32];
  __shared__ __align__(16) short Bs[4][256 * 32];
  int tid = threadIdx.x;
  int m0 = blockIdx.x * 256, n0 = blockIdx.y * 256;
  int wave = tid >> 6, lane = tid & 63;
  int l16 = lane & 15, quad = lane >> 4;
  int wm = (wave >> 2) * 128;  // 2 row-wave groups
  int wn = (wave & 3) * 64;    // 4 col-wave groups

  // Per-lane staging source offsets (shorts) for the 2 ST calls per operand.
  // Chunk c (16B) -> LDS slot (r=c>>2, s=c&3) <- global chunk (r, s^((r>>1)&3)).
  size_t offA[2], offB[2];
  int ldsOff[2];
#pragma unroll
  for (int p = 0; p < 2; ++p) {
    int c = p * 512 + tid;
    int r = c >> 2;
    int cg = (c & 3) ^ ((r >> 1) & 3);
    offA[p] = (size_t)(m0 + r) * K + cg * 8;
    offB[p] = (size_t)(n0 + r) * K + cg * 8;
    ldsOff[p] = (p * 512 + wave * 64) * 8;  // wave-uniform LDS base (shorts)
  }

  // Loop-invariant fragment read offsets (shorts): row R, k-chunk quad.
  int aoff[8], boff[4];
#pragma unroll
  for (int mi = 0; mi < 8; ++mi) {
    int R = wm + mi * 16 + l16;
    aoff[mi] = R * 32 + ((quad ^ ((R >> 1) & 3)) * 8);
  }
#pragma unroll
  for (int ni = 0; ni < 4; ++ni) {
    int R = wn + ni * 16 + l16;
    boff[ni] = R * 32 + ((quad ^ ((R >> 1) & 3)) * 8);
  }

  f32x4 acc[8][4];
#pragma unroll
  for (int i = 0; i < 8; ++i)
#pragma unroll
    for (int j = 0; j < 4; ++j)
#pragma unroll
      for (int r = 0; r < 4; ++r) acc[i][j][r] = 0.f;

#define STAGE(tt, bufc)                                                        \
  do {                                                                         \
    int kt_ = (tt) * 32;                                                       \
    GLOAD_LDS16(A + offA[0] + kt_, &As[bufc][0] + ldsOff[0]);                  \
    GLOAD_LDS16(A + offA[1] + kt_, &As[bufc][0] + ldsOff[1]);                  \
    GLOAD_LDS16(Bt + offB[0] + kt_, &Bs[bufc][0] + ldsOff[0]);                 \
    GLOAD_LDS16(Bt + offB[1] + kt_, &Bs[bufc][0] + ldsOff[1]);                 \
  } while (0)

#define TILE(tc, bufc, WAITN, DOSTAGE)                                         \
  do {                                                                         \
    asm volatile("s_waitcnt vmcnt(" #WAITN ")" ::: "memory");                  \
    __builtin_amdgcn_s_barrier();                                              \
    asm volatile("" ::: "memory");                                             \
    if (DOSTAGE) STAGE((tc) + 3, ((bufc) + 3) & 3);                            \
    bf16x8 af[8], bfv[4];                                                      \
    _Pragma("unroll") for (int mi = 0; mi < 8; ++mi)                           \
        af[mi] = *(const bf16x8*)&As[bufc][aoff[mi]];                          \
    _Pragma("unroll") for (int ni = 0; ni < 4; ++ni)                           \
        bfv[ni] = *(const bf16x8*)&Bs[bufc][boff[ni]];                         \
    __builtin_amdgcn_s_setprio(1);                                             \
    _Pragma("unroll") for (int mi = 0; mi < 8; ++mi)                           \
      _Pragma("unroll") for (int ni = 0; ni < 4; ++ni)                         \
        acc[mi][ni] = __builtin_amdgcn_mfma_f32_16x16x32_bf16(                 \
            af[mi], bfv[ni], acc[mi][ni], 0, 0, 0);                            \
    __builtin_amdgcn_s_setprio(0);                                             \
  } while (0)

  const int NT = K >> 5;  // 32 for K=1024
  // prologue: stage tiles 0..2 (12 loads in flight)
  STAGE(0, 0);
  STAGE(1, 1);
  STAGE(2, 2);

  int t4 = 0;
  for (; t4 + 8 <= NT; t4 += 4) {
    TILE(t4 + 0, 0, 8, 1);
    TILE(t4 + 1, 1, 8, 1);
    TILE(t4 + 2, 2, 8, 1);
    TILE(t4 + 3, 3, 8, 1);
  }
  // final 4 tiles (t4 == NT-4): epilogue drains 8 -> 8 -> 4 -> 0
  TILE(t4 + 0, 0, 8, 1);  // stages tile NT-1
  TILE(t4 + 1, 1, 8, 0);
  TILE(t4 + 2, 2, 4, 0);
  TILE(t4 + 3, 3, 0, 0);
#undef TILE
#undef STAGE

  // epilogue
#pragma unroll
  for (int ni = 0; ni < 4; ++ni) {
    int col = n0 + wn + ni * 16 + l16;
    float bv = bias[col];
#pragma unroll
    for (int mi = 0; mi < 8; ++mi) {
      int row0 = m0 + wm + mi * 16 + quad * 4;
#pragma unroll
      for (int r = 0; r < 4; ++r) {
        int row = row0 + r;
        float v = acc[mi][ni][r] + bv;
        if (mode == 2) {
          Cf[(size_t)row * Nn + col] = v + res[(size_t)row * Nn + col];
        } else {
          Cb[(size_t)row * Nn + col] = f2b(v);
        }
      }
    }
  }
}

// ---------------------------------------------------------------------------
// Cross-attention: per (b,h), 64 Q-rows per block (4 waves x 16 rows).
// All operands bf16, accum f32. LDS = exactly 64 KB.
// ---------------------------------------------------------------------------
__global__ __launch_bounds__(256) void attn_k(const u16* __restrict__ Q,
                                              const u16* __restrict__ Kt,
                                              const u16* __restrict__ VT,
                                              u16* __restrict__ Y) {
  __shared__ __align__(16) short KsPs[256 * 64];  // K tile; reused as P (64x256)
  __shared__ __align__(16) short Vt[64 * 256];    // V^T tile: [d][token]
  int tid = threadIdx.x;
  int t0 = blockIdx.x * 64, h = blockIdx.y, b = blockIdx.z;
  int wave = tid >> 6, lane = tid & 63;
  int l16 = lane & 15, quad = lane >> 4;
  int wb = wave * 16;

#pragma unroll
  for (int p = 0; p < 8; ++p) {
    int c = tid + p * 256;
    int n = c >> 3, cd = c & 7;
    *(int4*)&KsPs[n * 64 + ((cd ^ (n & 7)) * 8)] =
        *(const int4*)(Kt + ((size_t)(b * 256 + n)) * 1024 + h * 64 + cd * 8);
  }
#pragma unroll
  for (int p = 0; p < 8; ++p) {
    int c = tid + p * 256;
    int d = c >> 5, ch = c & 31;
    *(int4*)&Vt[d * 256 + ((ch ^ (d & 7)) * 8)] =
        *(const int4*)(VT + ((size_t)(b * 1024 + h * 64 + d)) * 256 + ch * 8);
  }
  const u16* qrow = Q + ((size_t)(b * 4096 + t0 + wb + l16)) * 1024 + h * 64;
  bf16x8 qf0 = *(const bf16x8*)(qrow + quad * 8);
  bf16x8 qf1 = *(const bf16x8*)(qrow + 32 + quad * 8);
  __syncthreads();

  f32x4 sa[16];
#pragma unroll
  for (int nt = 0; nt < 16; ++nt)
#pragma unroll
    for (int r = 0; r < 4; ++r) sa[nt][r] = 0.f;
#pragma unroll
  for (int ks = 0; ks < 2; ++ks) {
    bf16x8 af = ks ? qf1 : qf0;
#pragma unroll
    for (int nt = 0; nt < 16; ++nt) {
      int n = nt * 16 + l16;
      bf16x8 bfr = *(const bf16x8*)&KsPs[n * 64 + (((ks * 4 + quad) ^ (n & 7)) * 8)];
      sa[nt] = __builtin_amdgcn_mfma_f32_16x16x32_bf16(af, bfr, sa[nt], 0, 0, 0);
    }
  }
  __syncthreads();  // all waves done reading K before P overwrites it

#pragma unroll
  for (int r = 0; r < 4; ++r) {
    float mx = -3.0e38f;
#pragma unroll
    for (int nt = 0; nt < 16; ++nt) mx = fmaxf(mx, sa[nt][r]);
    mx = fmaxf(mx, __shfl_xor(mx, 1));
    mx = fmaxf(mx, __shfl_xor(mx, 2));
    mx = fmaxf(mx, __shfl_xor(mx, 4));
    mx = fmaxf(mx, __shfl_xor(mx, 8));
    float e[16];
    float sum = 0.f;
#pragma unroll
    for (int nt = 0; nt < 16; ++nt) {
      e[nt] = __expf((sa[nt][r] - mx) * 0.125f);
      sum += e[nt];
    }
    sum += __shfl_xor(sum, 1);
    sum += __shfl_xor(sum, 2);
    sum += __shfl_xor(sum, 4);
    sum += __shfl_xor(sum, 8);
    float rsc = 1.0f / sum;
    int prow = wb + quad * 4 + r;
#pragma unroll
    for (int nt = 0; nt < 16; ++nt) {
      int col = nt * 16 + l16;
      KsPs[prow * 256 + (((col >> 3) ^ (prow & 7)) * 8) + (col & 7)] =
          (short)f2b(e[nt] * rsc);
    }
  }
  __syncthreads();

  f32x4 ya[4];
#pragma unroll
  for (int j = 0; j < 4; ++j)
#pragma unroll
    for (int r = 0; r < 4; ++r) ya[j][r] = 0.f;
  int m = wb + l16;
#pragma unroll
  for (int kk = 0; kk < 8; ++kk) {
    bf16x8 af = *(const bf16x8*)&KsPs[m * 256 + (((kk * 4 + quad) ^ (m & 7)) * 8)];
#pragma unroll
    for (int j = 0; j < 4; ++j) {
      int d = j * 16 + l16;
      bf16x8 bfr = *(const bf16x8*)&Vt[d * 256 + (((kk * 4 + quad) ^ (d & 7)) * 8)];
      ya[j] = __builtin_amdgcn_mfma_f32_16x16x32_bf16(af, bfr, ya[j], 0, 0, 0);
    }
  }
#pragma unroll
  for (int j = 0; j < 4; ++j)
#pragma unroll
    for (int r = 0; r < 4; ++r)
      Y[((size_t)(b * 4096 + t0 + wb + quad * 4 + r)) * 1024 + h * 64 + j * 16 + l16] =
          f2b(ya[j][r]);
}

// ---------------------------------------------------------------------------
extern "C" void kernel_launch(void* const* d_in, const int* in_sizes, int n_in,
                              void* d_out, int out_size, void* d_ws, size_t ws_size,
                              hipStream_t stream) {
  const float* x       = (const float*)d_in[0];
  const float* xf      = (const float*)d_in[1];
  const float* emb     = (const float*)d_in[2];
  const float* norm_g  = (const float*)d_in[3];
  const float* norm_b  = (const float*)d_in[4];
  const float* tnorm_g = (const float*)d_in[5];
  const float* tnorm_b = (const float*)d_in[6];
  const float* Wq      = (const float*)d_in[7];
  const float* bq      = (const float*)d_in[8];
  const float* Wk      = (const float*)d_in[9];
  const float* bk      = (const float*)d_in[10];
  const float* Wv      = (const float*)d_in[11];
  const float* bv      = (const float*)d_in[12];
  const float* We      = (const float*)d_in[13];
  const float* be      = (const float*)d_in[14];
  const float* snorm_g = (const float*)d_in[15];
  const float* snorm_b = (const float*)d_in[16];
  const float* Wo      = (const float*)d_in[17];
  const float* bo      = (const float*)d_in[18];

  const size_t MB = 1024 * 1024;
  // d_out (64 MB f32) hosts transient bf16 buffers that die before the final
  // full-d_out write: Q (32 MB) + Wq^T/Wk^T/Wv^T transposed weights.
  char* dout = (char*)d_out;
  u16* qbuf = (u16*)(dout);             // 32 MB bf16 Q (dead after attn)
  u16* wqt  = (u16*)(dout + 32 * MB);   // 2 MB   (dead after Q-GEMM)
  u16* wkt  = (u16*)(dout + 34 * MB);   // 1.5 MB (dead after K-GEMM)
  u16* wvt  = (u16*)(dout + 36 * MB);   // 1.5 MB (dead after V-GEMM)
  float* out = (float*)d_out;

  // Workspace: ~39.6 MB total.
  char* ws = (char*)d_ws;
  u16* big1 = (u16*)(ws);                        // 32 MB: LN(x) -> y -> s
  u16* xfn  = (u16*)(ws + 32 * MB);              // 1.5 MB
  u16* kws  = (u16*)(ws + 33 * MB + 512 * 1024); // 2 MB  (B,256,1024)
  u16* vtws = (u16*)(ws + 35 * MB + 512 * 1024); // 2 MB  (B,1024,256)
  u16* wot  = (u16*)(ws + 37 * MB + 512 * 1024); // 2 MB  (needed during final GEMM)
  float* embo = (float*)(ws + 39 * MB + 512 * 1024); // 32 KB f32

  // weight transposes (f32 -> bf16, B-operand wants k-contiguous), one launch
  transpose4_k<<<dim3(32, 32, 4), dim3(32, 8), 0, stream>>>(
      Wq, Wk, Wv, Wo, wqt, wkt, wvt, wot);

  // layernorms (f32 -> bf16)
  ln_k<<<16384, 256, 0, stream>>>(x, norm_g, norm_b, big1, 1024);
  ln_k<<<1024, 256, 0, stream>>>(xf, tnorm_g, tnorm_b, xfn, 768);

  // projections: Q (256^2 deep-pipelined) -> d_out; K -> kws; V -> vtws
  gemm256_k<<<dim3(64, 4), 512, 0, stream>>>(big1, wqt, bq, nullptr, qbuf, nullptr, 16384, 1024, 1024, 0);
  gemm_bt_k<<<dim3(8, 8), 256, 0, stream>>>(xfn, wkt, bk, nullptr, kws, nullptr, 1024, 1024, 768, 0);
  gemm_bt_k<<<dim3(8, 8), 256, 0, stream>>>(xfn, wvt, bv, nullptr, vtws, nullptr, 1024, 1024, 768, 1);

  // emb -> scale/shift (f32)
  emb_k<<<dim3(8, 4), 256, 0, stream>>>(emb, We, be, embo);

  // attention: reads Q (=d_out lower half), writes y (bf16) -> big1
  attn_k<<<dim3(64, 16, 4), 256, 0, stream>>>(qbuf, kws, vtws, big1);

  // stylization in-place: big1 (y) -> big1 (s)
  style_k<<<16384, 256, 0, stream>>>(big1, snorm_g, snorm_b, embo, big1);

  // out projection + bias + residual(x, f32) -> d_out (f32, full overwrite)
  gemm256_k<<<dim3(64, 4), 512, 0, stream>>>(big1, wot, bo, x, nullptr, out, 16384, 1024, 1024, 2);
}

// Round 4
// 378.403 us; speedup vs baseline: 1.3576x; 1.2620x over previous
//
#include <hip/hip_runtime.h>

typedef unsigned short u16;
typedef short bf16x8 __attribute__((ext_vector_type(8)));
typedef float f32x4 __attribute__((ext_vector_type(4)));

// Problem constants: B=4, T=4096, D=1024, N=256, L=768, H=16, dh=64, TE=1024
// I/O dtype: float32 (per reference). Internal MFMA compute: bf16.

__device__ __forceinline__ float b2f(u16 u) {
  union { unsigned int u; float f; } x; x.u = ((unsigned int)u) << 16; return x.f;
}
__device__ __forceinline__ u16 f2b(float f) {
  union { float f; unsigned int u; } x; x.f = f;
  unsigned int u = x.u;
  return (u16)((u + 0x7FFFu + ((u >> 16) & 1u)) >> 16);  // RNE
}

// async global->LDS, 16B per lane. LDS dest = wave-uniform base + lane*16.
#define GLOAD_LDS16(g, l)                                                      \
  __builtin_amdgcn_global_load_lds(                                            \
      (const __attribute__((address_space(1))) unsigned int*)(g),              \
      (__attribute__((address_space(3))) unsigned int*)(l), 16, 0, 0)

// ---------------------------------------------------------------------------
// Fused 4-way transpose + f32->bf16: dst[C][R] = bf16(src[R][C]), C=1024.
// grid (32, 32, 4), block (32,8). z selects {Wq,Wk,Wv,Wo}; R in {1024,768}.
// Also zero-fills embo (8192 f32) so emb_k can atomicAdd split-K partials.
// ---------------------------------------------------------------------------
__global__ __launch_bounds__(256) void transpose4_k(
    const float* __restrict__ Wq, const float* __restrict__ Wk,
    const float* __restrict__ Wv, const float* __restrict__ Wo,
    u16* __restrict__ wqt, u16* __restrict__ wkt,
    u16* __restrict__ wvt, u16* __restrict__ wot,
    float* __restrict__ embo) {
  if (blockIdx.z == 0 && blockIdx.y == 0) {
    int idx = blockIdx.x * 256 + threadIdx.y * 32 + threadIdx.x;
    embo[idx] = 0.f;  // 32 blocks x 256 threads = 8192 = B*2D
  }
  const float* src; u16* dst; int R;
  switch (blockIdx.z) {
    case 0: src = Wq; dst = wqt; R = 1024; break;
    case 1: src = Wk; dst = wkt; R = 768;  break;
    case 2: src = Wv; dst = wvt; R = 768;  break;
    default: src = Wo; dst = wot; R = 1024; break;
  }
  int bx = blockIdx.x * 32, by = blockIdx.y * 32;
  if (by >= R) return;
  __shared__ float t[32][33];
  int x = threadIdx.x, y = threadIdx.y;
#pragma unroll
  for (int i = 0; i < 4; ++i)
    t[y * 4 + i][x] = src[(size_t)(by + y * 4 + i) * 1024 + bx + x];
  __syncthreads();
#pragma unroll
  for (int i = 0; i < 4; ++i)
    dst[(size_t)(bx + y * 4 + i) * R + by + x] = f2b(t[x][y * 4 + i]);
}

// ---------------------------------------------------------------------------
// Row LayerNorm, f32 in -> bf16 out. One block per row. C in {768, 1024}.
// ---------------------------------------------------------------------------
__global__ __launch_bounds__(256) void ln_k(const float* __restrict__ in,
                                            const float* __restrict__ g,
                                            const float* __restrict__ bta,
                                            u16* __restrict__ out, int C) {
  int row = blockIdx.x, tid = threadIdx.x;
  const float* p = in + (size_t)row * C;
  int i0 = tid * 4;
  bool act = i0 < C;
  float v0 = 0.f, v1 = 0.f, v2 = 0.f, v3 = 0.f;
  if (act) {
    float4 u = *(const float4*)(p + i0);
    v0 = u.x; v1 = u.y; v2 = u.z; v3 = u.w;
  }
  float s = v0 + v1 + v2 + v3;
  float q = v0 * v0 + v1 * v1 + v2 * v2 + v3 * v3;
  __shared__ float red[8];
#pragma unroll
  for (int m = 32; m; m >>= 1) { s += __shfl_xor(s, m); q += __shfl_xor(q, m); }
  if ((tid & 63) == 0) { red[tid >> 6] = s; red[4 + (tid >> 6)] = q; }
  __syncthreads();
  s = red[0] + red[1] + red[2] + red[3];
  q = red[4] + red[5] + red[6] + red[7];
  float invC = 1.0f / (float)C;
  float mu = s * invC;
  float rs = rsqrtf(q * invC - mu * mu + 1e-5f);
  if (act) {
    float4 ug = *(const float4*)(g + i0);
    float4 ub = *(const float4*)(bta + i0);
    ushort4 o;
    o.x = f2b((v0 - mu) * rs * ug.x + ub.x);
    o.y = f2b((v1 - mu) * rs * ug.y + ub.y);
    o.z = f2b((v2 - mu) * rs * ug.z + ub.z);
    o.w = f2b((v3 - mu) * rs * ug.w + ub.w);
    *(ushort4*)(out + (size_t)row * C + i0) = o;
  }
}

// ---------------------------------------------------------------------------
// Stylization (in-place safe): out = bf16( silu( LN(y)*(1+scale_b) + shift_b ) ).
// ---------------------------------------------------------------------------
__global__ __launch_bounds__(256) void style_k(const u16* __restrict__ y,
                                               const float* __restrict__ g,
                                               const float* __restrict__ bta,
                                               const float* __restrict__ embo,
                                               u16* __restrict__ out) {
  int row = blockIdx.x, tid = threadIdx.x;
  int b = row >> 12;  // T=4096
  const u16* p = y + (size_t)row * 1024;
  int i0 = tid * 4;
  ushort4 u = *(const ushort4*)(p + i0);
  float v0 = b2f(u.x), v1 = b2f(u.y), v2 = b2f(u.z), v3 = b2f(u.w);
  float s = v0 + v1 + v2 + v3;
  float q = v0 * v0 + v1 * v1 + v2 * v2 + v3 * v3;
  __shared__ float red[8];
#pragma unroll
  for (int m = 32; m; m >>= 1) { s += __shfl_xor(s, m); q += __shfl_xor(q, m); }
  if ((tid & 63) == 0) { red[tid >> 6] = s; red[4 + (tid >> 6)] = q; }
  __syncthreads();
  s = red[0] + red[1] + red[2] + red[3];
  q = red[4] + red[5] + red[6] + red[7];
  const float invC = 1.0f / 1024.0f;
  float mu = s * invC;
  float rs = rsqrtf(q * invC - mu * mu + 1e-5f);
  float4 ug = *(const float4*)(g + i0);
  float4 ub = *(const float4*)(bta + i0);
  float4 sc = *(const float4*)(embo + b * 2048 + i0);
  float4 sh = *(const float4*)(embo + b * 2048 + 1024 + i0);
  float h0 = ((v0 - mu) * rs * ug.x + ub.x) * (1.0f + sc.x) + sh.x;
  float h1 = ((v1 - mu) * rs * ug.y + ub.y) * (1.0f + sc.y) + sh.y;
  float h2 = ((v2 - mu) * rs * ug.z + ub.z) * (1.0f + sc.z) + sh.z;
  float h3 = ((v3 - mu) * rs * ug.w + ub.w) * (1.0f + sc.w) + sh.w;
  ushort4 o;
  o.x = f2b(h0 / (1.0f + __expf(-h0)));
  o.y = f2b(h1 / (1.0f + __expf(-h1)));
  o.z = f2b(h2 / (1.0f + __expf(-h2)));
  o.w = f2b(h3 / (1.0f + __expf(-h3)));
  *(ushort4*)(out + (size_t)row * 1024 + i0) = o;
}

// ---------------------------------------------------------------------------
// Split-K emb projection: embo[b][j] += sum_{i in split} silu(emb[b][i])*We[i][j]
// grid (8, 4, 8): j-block (256 cols), b, i-split (128 rows). embo pre-zeroed
// by transpose4_k; split 0 adds the bias. 256 blocks -> latency hidden.
// ---------------------------------------------------------------------------
__global__ __launch_bounds__(256) void emb_k(const float* __restrict__ emb,
                                             const float* __restrict__ We,
                                             const float* __restrict__ be,
                                             float* __restrict__ embo) {
  int b = blockIdx.y, tid = threadIdx.x;
  int j = blockIdx.x * 256 + tid;
  int i0 = blockIdx.z * 128;
  __shared__ float se[128];
  if (tid < 128) {
    float v = emb[b * 1024 + i0 + tid];
    se[tid] = v / (1.0f + __expf(-v));
  }
  __syncthreads();
  float acc = (blockIdx.z == 0) ? be[j] : 0.f;
#pragma unroll 8
  for (int i = 0; i < 128; ++i) acc += se[i] * We[(size_t)(i0 + i) * 2048 + j];
  atomicAdd(&embo[b * 2048 + j], acc);
}

// ---------------------------------------------------------------------------
// GEMM  C[M][Nn] = A[M][K] @ Bt[Nn][K]^T + bias(f32), A/Bt bf16.
// 128x128 tile, m97 structure. Kept for the small K/V projections
// (M=1024: needs the finer grid for CU coverage).
// mode 0: Cb[row*Nn+col] (bf16)
// mode 1: V-transpose store: Cb[((row>>8)*1024 + col)*256 + (row&255)] (bf16)
// mode 2: Cf[row*Nn+col] = acc + bias + res[row*Nn+col]  (f32 out, f32 res)
// ---------------------------------------------------------------------------
__global__ __launch_bounds__(256) void gemm_bt_k(const u16* __restrict__ A,
                                                 const u16* __restrict__ Bt,
                                                 const float* __restrict__ bias,
                                                 const float* __restrict__ res,
                                                 u16* __restrict__ Cb,
                                                 float* __restrict__ Cf,
                                                 int M, int Nn, int K, int mode) {
  __shared__ __align__(16) short As[128 * 64];
  __shared__ __align__(16) short Bs[128 * 64];
  int tid = threadIdx.x;
  int m0 = blockIdx.x * 128, n0 = blockIdx.y * 128;
  int wave = tid >> 6, lane = tid & 63;
  int l16 = lane & 15, quad = lane >> 4;
  int wm = (wave >> 1) * 64, wn = (wave & 1) * 64;

  f32x4 acc[4][4];
#pragma unroll
  for (int i = 0; i < 4; ++i)
#pragma unroll
    for (int j = 0; j < 4; ++j)
#pragma unroll
      for (int r = 0; r < 4; ++r) acc[i][j][r] = 0.f;

  for (int kt = 0; kt < K; kt += 64) {
#pragma unroll
    for (int p = 0; p < 4; ++p) {
      int c = p * 256 + tid;
      int r = c >> 3;
      int cd = ((c & 7) ^ (r & 7)) * 8;   // swizzled global column (shorts)
      int lb = (p * 256 + wave * 64) * 8; // wave's LDS chunk base (shorts)
      GLOAD_LDS16(A + (size_t)(m0 + r) * K + kt + cd, As + lb);
      GLOAD_LDS16(Bt + (size_t)(n0 + r) * K + kt + cd, Bs + lb);
    }
    __syncthreads();
#pragma unroll
    for (int ks = 0; ks < 2; ++ks) {
      int swz = ((ks * 4 + quad) ^ (l16 & 7)) * 8;
      bf16x8 af[4], bfr[4];
#pragma unroll
      for (int i = 0; i < 4; ++i)
        af[i] = *(const bf16x8*)&As[(wm + i * 16 + l16) * 64 + swz];
#pragma unroll
      for (int j = 0; j < 4; ++j)
        bfr[j] = *(const bf16x8*)&Bs[(wn + j * 16 + l16) * 64 + swz];
#pragma unroll
      for (int i = 0; i < 4; ++i)
#pragma unroll
        for (int j = 0; j < 4; ++j)
          acc[i][j] = __builtin_amdgcn_mfma_f32_16x16x32_bf16(af[i], bfr[j], acc[i][j], 0, 0, 0);
    }
    __syncthreads();
  }

#pragma unroll
  for (int j = 0; j < 4; ++j) {
    int col = n0 + wn + j * 16 + l16;
    float bv = bias[col];
#pragma unroll
    for (int i = 0; i < 4; ++i) {
      int row0 = m0 + wm + i * 16 + quad * 4;
#pragma unroll
      for (int r = 0; r < 4; ++r) {
        int row = row0 + r;
        float v = acc[i][j][r] + bv;
        if (mode == 2) {
          Cf[(size_t)row * Nn + col] = v + res[(size_t)row * Nn + col];
        } else if (mode == 1) {
          Cb[((size_t)((row >> 8) * 1024 + col)) * 256 + (row & 255)] = f2b(v);
        } else {
          Cb[(size_t)row * Nn + col] = f2b(v);
        }
      }
    }
  }
}

// ---------------------------------------------------------------------------
// 256x256-tile deep-pipelined GEMM for the two big 16384x1024x1024 GEMMs.
// BK=32, QUADRUPLE-buffered LDS (4 x 16KB x 2 operands = 128 KiB), 8 waves
// (2M x 4N), per-wave output 128x64 (acc[8][4]).
// Per K-tile: s_waitcnt vmcnt(8); s_barrier; stage t+3; 12 ds_read_b128;
// 32 MFMA (setprio 1). Counted vmcnt never 0 in main loop; depth-3 prefetch;
// one barrier per tile.
// Epilogue: LDS-transpose through the (now free) 128 KiB staging buffer so
// res loads + C stores are fully coalesced (1KB float4 rows per wave),
// replacing the former 64B-segment scatter. Bank swizzle col^=((row>>2)&3)<<3
// keeps the fragment-write phase at worst 2-way (free).
// grid (M/256, Nn/256) = (64,4) -> 1 block/CU, all co-resident.
// mode 0: Cb = bf16(acc+bias);  mode 2: Cf = acc+bias+res (f32).
// ---------------------------------------------------------------------------
__global__ __launch_bounds__(512, 2) void gemm256_k(const u16* __restrict__ A,
                                                    const u16* __restrict__ Bt,
                                                    const float* __restrict__ bias,
                                                    const float* __restrict__ res,
                                                    u16* __restrict__ Cb,
                                                    float* __restrict__ Cf,
                                                    int M, int Nn, int K, int mode) {
  __shared__ __align__(16) short smem[2][4][256 * 32];  // [A/B][buf][tile]
  int tid = threadIdx.x;
  int m0 = blockIdx.x * 256, n0 = blockIdx.y * 256;
  int wave = tid >> 6, lane = tid & 63;
  int l16 = lane & 15, quad = lane >> 4;
  int wm = (wave >> 2) * 128;  // 2 row-wave groups
  int wn = (wave & 3) * 64;    // 4 col-wave groups

  // Per-lane staging source offsets (shorts) for the 2 ST calls per operand.
  // Chunk c (16B) -> LDS slot (r=c>>2, s=c&3) <- global chunk (r, s^((r>>1)&3)).
  size_t offA[2], offB[2];
  int ldsOff[2];
#pragma unroll
  for (int p = 0; p < 2; ++p) {
    int c = p * 512 + tid;
    int r = c >> 2;
    int cg = (c & 3) ^ ((r >> 1) & 3);
    offA[p] = (size_t)(m0 + r) * K + cg * 8;
    offB[p] = (size_t)(n0 + r) * K + cg * 8;
    ldsOff[p] = (p * 512 + wave * 64) * 8;  // wave-uniform LDS base (shorts)
  }

  // Loop-invariant fragment read offsets (shorts): row R, k-chunk quad.
  int aoff[8], boff[4];
#pragma unroll
  for (int mi = 0; mi < 8; ++mi) {
    int R = wm + mi * 16 + l16;
    aoff[mi] = R * 32 + ((quad ^ ((R >> 1) & 3)) * 8);
  }
#pragma unroll
  for (int ni = 0; ni < 4; ++ni) {
    int R = wn + ni * 16 + l16;
    boff[ni] = R * 32 + ((quad ^ ((R >> 1) & 3)) * 8);
  }

  f32x4 acc[8][4];
#pragma unroll
  for (int i = 0; i < 8; ++i)
#pragma unroll
    for (int j = 0; j < 4; ++j)
#pragma unroll
      for (int r = 0; r < 4; ++r) acc[i][j][r] = 0.f;

#define STAGE(tt, bufc)                                                        \
  do {                                                                         \
    int kt_ = (tt) * 32;                                                       \
    GLOAD_LDS16(A + offA[0] + kt_, &smem[0][bufc][0] + ldsOff[0]);             \
    GLOAD_LDS16(A + offA[1] + kt_, &smem[0][bufc][0] + ldsOff[1]);             \
    GLOAD_LDS16(Bt + offB[0] + kt_, &smem[1][bufc][0] + ldsOff[0]);            \
    GLOAD_LDS16(Bt + offB[1] + kt_, &smem[1][bufc][0] + ldsOff[1]);            \
  } while (0)

#define TILE(tc, bufc, WAITN, DOSTAGE)                                         \
  do {                                                                         \
    asm volatile("s_waitcnt vmcnt(" #WAITN ")" ::: "memory");                  \
    __builtin_amdgcn_s_barrier();                                              \
    asm volatile("" ::: "memory");                                             \
    if (DOSTAGE) STAGE((tc) + 3, ((bufc) + 3) & 3);                            \
    bf16x8 af[8], bfv[4];                                                      \
    _Pragma("unroll") for (int mi = 0; mi < 8; ++mi)                           \
        af[mi] = *(const bf16x8*)&smem[0][bufc][aoff[mi]];                     \
    _Pragma("unroll") for (int ni = 0; ni < 4; ++ni)                           \
        bfv[ni] = *(const bf16x8*)&smem[1][bufc][boff[ni]];                    \
    __builtin_amdgcn_s_setprio(1);                                             \
    _Pragma("unroll") for (int mi = 0; mi < 8; ++mi)                           \
      _Pragma("unroll") for (int ni = 0; ni < 4; ++ni)                         \
        acc[mi][ni] = __builtin_amdgcn_mfma_f32_16x16x32_bf16(                 \
            af[mi], bfv[ni], acc[mi][ni], 0, 0, 0);                            \
    __builtin_amdgcn_s_setprio(0);                                             \
  } while (0)

  const int NT = K >> 5;  // 32 for K=1024
  // prologue: stage tiles 0..2 (12 loads in flight)
  STAGE(0, 0);
  STAGE(1, 1);
  STAGE(2, 2);

  int t4 = 0;
  for (; t4 + 8 <= NT; t4 += 4) {
    TILE(t4 + 0, 0, 8, 1);
    TILE(t4 + 1, 1, 8, 1);
    TILE(t4 + 2, 2, 8, 1);
    TILE(t4 + 3, 3, 8, 1);
  }
  // final 4 tiles (t4 == NT-4): epilogue drains 8 -> 8 -> 4 -> 0
  TILE(t4 + 0, 0, 8, 1);  // stages tile NT-1
  TILE(t4 + 1, 1, 8, 0);
  TILE(t4 + 2, 2, 4, 0);
  TILE(t4 + 3, 3, 0, 0);
#undef TILE
#undef STAGE

  // ---- coalesced epilogue via LDS transpose -------------------------------
  // eps = f32[128][256] view of the whole staging LDS (exactly 128 KiB).
  // Two halves of 128 rows; fragment writes use col ^ ((row>>2)&3)<<3.
  float* eps = (float*)&smem[0][0][0];
  float bv[4];
#pragma unroll
  for (int ni = 0; ni < 4; ++ni) bv[ni] = bias[n0 + wn + ni * 16 + l16];

#pragma unroll
  for (int half = 0; half < 2; ++half) {
    __syncthreads();  // prior LDS reads (main loop / prev half) done
    if ((wave >> 2) == half) {
#pragma unroll
      for (int mi = 0; mi < 8; ++mi) {
#pragma unroll
        for (int ni = 0; ni < 4; ++ni) {
          int col = wn + ni * 16 + l16;
#pragma unroll
          for (int r = 0; r < 4; ++r) {
            int row = mi * 16 + quad * 4 + r;
            eps[row * 256 + (col ^ (((row >> 2) & 3) << 3))] =
                acc[mi][ni][r] + bv[ni];
          }
        }
      }
    }
    __syncthreads();
#pragma unroll
    for (int p = 0; p < 16; ++p) {
      int row = wave * 16 + p;
      int grow = m0 + half * 128 + row;
      int colb = (lane * 4) ^ (((row >> 2) & 3) << 3);
      f32x4 v = *(const f32x4*)&eps[row * 256 + colb];
      if (mode == 2) {
        float4 rv = ((const float4*)&res[(size_t)grow * Nn + n0])[lane];
        float4 o;
        o.x = v[0] + rv.x; o.y = v[1] + rv.y;
        o.z = v[2] + rv.z; o.w = v[3] + rv.w;
        ((float4*)&Cf[(size_t)grow * Nn + n0])[lane] = o;
      } else {
        ushort4 o;
        o.x = f2b(v[0]); o.y = f2b(v[1]); o.z = f2b(v[2]); o.w = f2b(v[3]);
        ((ushort4*)&Cb[(size_t)grow * Nn + n0])[lane] = o;
      }
    }
  }
}

// ---------------------------------------------------------------------------
// Cross-attention: per (b,h), 64 Q-rows per block (4 waves x 16 rows).
// All operands bf16, accum f32. LDS = exactly 64 KB.
// ---------------------------------------------------------------------------
__global__ __launch_bounds__(256) void attn_k(const u16* __restrict__ Q,
                                              const u16* __restrict__ Kt,
                                              const u16* __restrict__ VT,
                                              u16* __restrict__ Y) {
  __shared__ __align__(16) short KsPs[256 * 64];  // K tile; reused as P (64x256)
  __shared__ __align__(16) short Vt[64 * 256];    // V^T tile: [d][token]
  int tid = threadIdx.x;
  int t0 = blockIdx.x * 64, h = blockIdx.y, b = blockIdx.z;
  int wave = tid >> 6, lane = tid & 63;
  int l16 = lane & 15, quad = lane >> 4;
  int wb = wave * 16;

#pragma unroll
  for (int p = 0; p < 8; ++p) {
    int c = tid + p * 256;
    int n = c >> 3, cd = c & 7;
    *(int4*)&KsPs[n * 64 + ((cd ^ (n & 7)) * 8)] =
        *(const int4*)(Kt + ((size_t)(b * 256 + n)) * 1024 + h * 64 + cd * 8);
  }
#pragma unroll
  for (int p = 0; p < 8; ++p) {
    int c = tid + p * 256;
    int d = c >> 5, ch = c & 31;
    *(int4*)&Vt[d * 256 + ((ch ^ (d & 7)) * 8)] =
        *(const int4*)(VT + ((size_t)(b * 1024 + h * 64 + d)) * 256 + ch * 8);
  }
  const u16* qrow = Q + ((size_t)(b * 4096 + t0 + wb + l16)) * 1024 + h * 64;
  bf16x8 qf0 = *(const bf16x8*)(qrow + quad * 8);
  bf16x8 qf1 = *(const bf16x8*)(qrow + 32 + quad * 8);
  __syncthreads();

  f32x4 sa[16];
#pragma unroll
  for (int nt = 0; nt < 16; ++nt)
#pragma unroll
    for (int r = 0; r < 4; ++r) sa[nt][r] = 0.f;
#pragma unroll
  for (int ks = 0; ks < 2; ++ks) {
    bf16x8 af = ks ? qf1 : qf0;
#pragma unroll
    for (int nt = 0; nt < 16; ++nt) {
      int n = nt * 16 + l16;
      bf16x8 bfr = *(const bf16x8*)&KsPs[n * 64 + (((ks * 4 + quad) ^ (n & 7)) * 8)];
      sa[nt] = __builtin_amdgcn_mfma_f32_16x16x32_bf16(af, bfr, sa[nt], 0, 0, 0);
    }
  }
  __syncthreads();  // all waves done reading K before P overwrites it

#pragma unroll
  for (int r = 0; r < 4; ++r) {
    float mx = -3.0e38f;
#pragma unroll
    for (int nt = 0; nt < 16; ++nt) mx = fmaxf(mx, sa[nt][r]);
    mx = fmaxf(mx, __shfl_xor(mx, 1));
    mx = fmaxf(mx, __shfl_xor(mx, 2));
    mx = fmaxf(mx, __shfl_xor(mx, 4));
    mx = fmaxf(mx, __shfl_xor(mx, 8));
    float e[16];
    float sum = 0.f;
#pragma unroll
    for (int nt = 0; nt < 16; ++nt) {
      e[nt] = __expf((sa[nt][r] - mx) * 0.125f);
      sum += e[nt];
    }
    sum += __shfl_xor(sum, 1);
    sum += __shfl_xor(sum, 2);
    sum += __shfl_xor(sum, 4);
    sum += __shfl_xor(sum, 8);
    float rsc = 1.0f / sum;
    int prow = wb + quad * 4 + r;
#pragma unroll
    for (int nt = 0; nt < 16; ++nt) {
      int col = nt * 16 + l16;
      KsPs[prow * 256 + (((col >> 3) ^ (prow & 7)) * 8) + (col & 7)] =
          (short)f2b(e[nt] * rsc);
    }
  }
  __syncthreads();

  f32x4 ya[4];
#pragma unroll
  for (int j = 0; j < 4; ++j)
#pragma unroll
    for (int r = 0; r < 4; ++r) ya[j][r] = 0.f;
  int m = wb + l16;
#pragma unroll
  for (int kk = 0; kk < 8; ++kk) {
    bf16x8 af = *(const bf16x8*)&KsPs[m * 256 + (((kk * 4 + quad) ^ (m & 7)) * 8)];
#pragma unroll
    for (int j = 0; j < 4; ++j) {
      int d = j * 16 + l16;
      bf16x8 bfr = *(const bf16x8*)&Vt[d * 256 + (((kk * 4 + quad) ^ (d & 7)) * 8)];
      ya[j] = __builtin_amdgcn_mfma_f32_16x16x32_bf16(af, bfr, ya[j], 0, 0, 0);
    }
  }
#pragma unroll
  for (int j = 0; j < 4; ++j)
#pragma unroll
    for (int r = 0; r < 4; ++r)
      Y[((size_t)(b * 4096 + t0 + wb + quad * 4 + r)) * 1024 + h * 64 + j * 16 + l16] =
          f2b(ya[j][r]);
}

// ---------------------------------------------------------------------------
extern "C" void kernel_launch(void* const* d_in, const int* in_sizes, int n_in,
                              void* d_out, int out_size, void* d_ws, size_t ws_size,
                              hipStream_t stream) {
  const float* x       = (const float*)d_in[0];
  const float* xf      = (const float*)d_in[1];
  const float* emb     = (const float*)d_in[2];
  const float* norm_g  = (const float*)d_in[3];
  const float* norm_b  = (const float*)d_in[4];
  const float* tnorm_g = (const float*)d_in[5];
  const float* tnorm_b = (const float*)d_in[6];
  const float* Wq      = (const float*)d_in[7];
  const float* bq      = (const float*)d_in[8];
  const float* Wk      = (const float*)d_in[9];
  const float* bk      = (const float*)d_in[10];
  const float* Wv      = (const float*)d_in[11];
  const float* bv      = (const float*)d_in[12];
  const float* We      = (const float*)d_in[13];
  const float* be      = (const float*)d_in[14];
  const float* snorm_g = (const float*)d_in[15];
  const float* snorm_b = (const float*)d_in[16];
  const float* Wo      = (const float*)d_in[17];
  const float* bo      = (const float*)d_in[18];

  const size_t MB = 1024 * 1024;
  // d_out (64 MB f32) hosts transient bf16 buffers that die before the final
  // full-d_out write: Q (32 MB) + Wq^T/Wk^T/Wv^T transposed weights.
  char* dout = (char*)d_out;
  u16* qbuf = (u16*)(dout);             // 32 MB bf16 Q (dead after attn)
  u16* wqt  = (u16*)(dout + 32 * MB);   // 2 MB   (dead after Q-GEMM)
  u16* wkt  = (u16*)(dout + 34 * MB);   // 1.5 MB (dead after K-GEMM)
  u16* wvt  = (u16*)(dout + 36 * MB);   // 1.5 MB (dead after V-GEMM)
  float* out = (float*)d_out;

  // Workspace: ~39.6 MB total.
  char* ws = (char*)d_ws;
  u16* big1 = (u16*)(ws);                        // 32 MB: LN(x) -> y -> s
  u16* xfn  = (u16*)(ws + 32 * MB);              // 1.5 MB
  u16* kws  = (u16*)(ws + 33 * MB + 512 * 1024); // 2 MB  (B,256,1024)
  u16* vtws = (u16*)(ws + 35 * MB + 512 * 1024); // 2 MB  (B,1024,256)
  u16* wot  = (u16*)(ws + 37 * MB + 512 * 1024); // 2 MB  (needed during final GEMM)
  float* embo = (float*)(ws + 39 * MB + 512 * 1024); // 32 KB f32

  // weight transposes (f32 -> bf16) + embo zero-fill, one launch
  transpose4_k<<<dim3(32, 32, 4), dim3(32, 8), 0, stream>>>(
      Wq, Wk, Wv, Wo, wqt, wkt, wvt, wot, embo);

  // layernorms (f32 -> bf16)
  ln_k<<<16384, 256, 0, stream>>>(x, norm_g, norm_b, big1, 1024);
  ln_k<<<1024, 256, 0, stream>>>(xf, tnorm_g, tnorm_b, xfn, 768);

  // projections: Q (256^2 deep-pipelined) -> d_out; K -> kws; V -> vtws
  gemm256_k<<<dim3(64, 4), 512, 0, stream>>>(big1, wqt, bq, nullptr, qbuf, nullptr, 16384, 1024, 1024, 0);
  gemm_bt_k<<<dim3(8, 8), 256, 0, stream>>>(xfn, wkt, bk, nullptr, kws, nullptr, 1024, 1024, 768, 0);
  gemm_bt_k<<<dim3(8, 8), 256, 0, stream>>>(xfn, wvt, bv, nullptr, vtws, nullptr, 1024, 1024, 768, 1);

  // emb -> scale/shift (f32), split-K atomic
  emb_k<<<dim3(8, 4, 8), 256, 0, stream>>>(emb, We, be, embo);

  // attention: reads Q (=d_out lower half), writes y (bf16) -> big1
  attn_k<<<dim3(64, 16, 4), 256, 0, stream>>>(qbuf, kws, vtws, big1);

  // stylization in-place: big1 (y) -> big1 (s)
  style_k<<<16384, 256, 0, stream>>>(big1, snorm_g, snorm_b, embo, big1);

  // out projection + bias + residual(x, f32) -> d_out (f32, full overwrite)
  gemm256_k<<<dim3(64, 4), 512, 0, stream>>>(big1, wot, bo, x, nullptr, out, 16384, 1024, 1024, 2);
}

// Round 5
// 376.675 us; speedup vs baseline: 1.3639x; 1.0046x over previous
//
#include <hip/hip_runtime.h>

typedef unsigned short u16;
typedef short bf16x8 __attribute__((ext_vector_type(8)));
typedef float f32x4 __attribute__((ext_vector_type(4)));

// Problem constants: B=4, T=4096, D=1024, N=256, L=768, H=16, dh=64, TE=1024
// I/O dtype: float32 (per reference). Internal MFMA compute: bf16.

__device__ __forceinline__ float b2f(u16 u) {
  union { unsigned int u; float f; } x; x.u = ((unsigned int)u) << 16; return x.f;
}
__device__ __forceinline__ u16 f2b(float f) {
  union { float f; unsigned int u; } x; x.f = f;
  unsigned int u = x.u;
  return (u16)((u + 0x7FFFu + ((u >> 16) & 1u)) >> 16);  // RNE
}

// async global->LDS, 16B per lane. LDS dest = wave-uniform base + lane*16.
#define GLOAD_LDS16(g, l)                                                      \
  __builtin_amdgcn_global_load_lds(                                            \
      (const __attribute__((address_space(1))) unsigned int*)(g),              \
      (__attribute__((address_space(3))) unsigned int*)(l), 16, 0, 0)

// ---------------------------------------------------------------------------
// Fused 4-way transpose + f32->bf16: dst[C][R] = bf16(src[R][C]), C=1024.
// grid (32, 32, 4), block (32,8). z selects {Wq,Wk,Wv,Wo}; R in {1024,768}.
// Also zero-fills embo (8192 f32) so emb_k can atomicAdd split-K partials.
// ---------------------------------------------------------------------------
__global__ __launch_bounds__(256) void transpose4_k(
    const float* __restrict__ Wq, const float* __restrict__ Wk,
    const float* __restrict__ Wv, const float* __restrict__ Wo,
    u16* __restrict__ wqt, u16* __restrict__ wkt,
    u16* __restrict__ wvt, u16* __restrict__ wot,
    float* __restrict__ embo) {
  if (blockIdx.z == 0 && blockIdx.y == 0) {
    int idx = blockIdx.x * 256 + threadIdx.y * 32 + threadIdx.x;
    embo[idx] = 0.f;  // 32 blocks x 256 threads = 8192 = B*2D
  }
  const float* src; u16* dst; int R;
  switch (blockIdx.z) {
    case 0: src = Wq; dst = wqt; R = 1024; break;
    case 1: src = Wk; dst = wkt; R = 768;  break;
    case 2: src = Wv; dst = wvt; R = 768;  break;
    default: src = Wo; dst = wot; R = 1024; break;
  }
  int bx = blockIdx.x * 32, by = blockIdx.y * 32;
  if (by >= R) return;
  __shared__ float t[32][33];
  int x = threadIdx.x, y = threadIdx.y;
#pragma unroll
  for (int i = 0; i < 4; ++i)
    t[y * 4 + i][x] = src[(size_t)(by + y * 4 + i) * 1024 + bx + x];
  __syncthreads();
#pragma unroll
  for (int i = 0; i < 4; ++i)
    dst[(size_t)(bx + y * 4 + i) * R + by + x] = f2b(t[x][y * 4 + i]);
}

// ---------------------------------------------------------------------------
// Row LayerNorm, f32 in -> bf16 out. One block per row. C in {768, 1024}.
// ---------------------------------------------------------------------------
__global__ __launch_bounds__(256) void ln_k(const float* __restrict__ in,
                                            const float* __restrict__ g,
                                            const float* __restrict__ bta,
                                            u16* __restrict__ out, int C) {
  int row = blockIdx.x, tid = threadIdx.x;
  const float* p = in + (size_t)row * C;
  int i0 = tid * 4;
  bool act = i0 < C;
  float v0 = 0.f, v1 = 0.f, v2 = 0.f, v3 = 0.f;
  if (act) {
    float4 u = *(const float4*)(p + i0);
    v0 = u.x; v1 = u.y; v2 = u.z; v3 = u.w;
  }
  float s = v0 + v1 + v2 + v3;
  float q = v0 * v0 + v1 * v1 + v2 * v2 + v3 * v3;
  __shared__ float red[8];
#pragma unroll
  for (int m = 32; m; m >>= 1) { s += __shfl_xor(s, m); q += __shfl_xor(q, m); }
  if ((tid & 63) == 0) { red[tid >> 6] = s; red[4 + (tid >> 6)] = q; }
  __syncthreads();
  s = red[0] + red[1] + red[2] + red[3];
  q = red[4] + red[5] + red[6] + red[7];
  float invC = 1.0f / (float)C;
  float mu = s * invC;
  float rs = rsqrtf(q * invC - mu * mu + 1e-5f);
  if (act) {
    float4 ug = *(const float4*)(g + i0);
    float4 ub = *(const float4*)(bta + i0);
    ushort4 o;
    o.x = f2b((v0 - mu) * rs * ug.x + ub.x);
    o.y = f2b((v1 - mu) * rs * ug.y + ub.y);
    o.z = f2b((v2 - mu) * rs * ug.z + ub.z);
    o.w = f2b((v3 - mu) * rs * ug.w + ub.w);
    *(ushort4*)(out + (size_t)row * C + i0) = o;
  }
}

// ---------------------------------------------------------------------------
// Stylization (in-place safe): out = bf16( silu( LN(y)*(1+scale_b) + shift_b ) ).
// ---------------------------------------------------------------------------
__global__ __launch_bounds__(256) void style_k(const u16* __restrict__ y,
                                               const float* __restrict__ g,
                                               const float* __restrict__ bta,
                                               const float* __restrict__ embo,
                                               u16* __restrict__ out) {
  int row = blockIdx.x, tid = threadIdx.x;
  int b = row >> 12;  // T=4096
  const u16* p = y + (size_t)row * 1024;
  int i0 = tid * 4;
  ushort4 u = *(const ushort4*)(p + i0);
  float v0 = b2f(u.x), v1 = b2f(u.y), v2 = b2f(u.z), v3 = b2f(u.w);
  float s = v0 + v1 + v2 + v3;
  float q = v0 * v0 + v1 * v1 + v2 * v2 + v3 * v3;
  __shared__ float red[8];
#pragma unroll
  for (int m = 32; m; m >>= 1) { s += __shfl_xor(s, m); q += __shfl_xor(q, m); }
  if ((tid & 63) == 0) { red[tid >> 6] = s; red[4 + (tid >> 6)] = q; }
  __syncthreads();
  s = red[0] + red[1] + red[2] + red[3];
  q = red[4] + red[5] + red[6] + red[7];
  const float invC = 1.0f / 1024.0f;
  float mu = s * invC;
  float rs = rsqrtf(q * invC - mu * mu + 1e-5f);
  float4 ug = *(const float4*)(g + i0);
  float4 ub = *(const float4*)(bta + i0);
  float4 sc = *(const float4*)(embo + b * 2048 + i0);
  float4 sh = *(const float4*)(embo + b * 2048 + 1024 + i0);
  float h0 = ((v0 - mu) * rs * ug.x + ub.x) * (1.0f + sc.x) + sh.x;
  float h1 = ((v1 - mu) * rs * ug.y + ub.y) * (1.0f + sc.y) + sh.y;
  float h2 = ((v2 - mu) * rs * ug.z + ub.z) * (1.0f + sc.z) + sh.z;
  float h3 = ((v3 - mu) * rs * ug.w + ub.w) * (1.0f + sc.w) + sh.w;
  ushort4 o;
  o.x = f2b(h0 / (1.0f + __expf(-h0)));
  o.y = f2b(h1 / (1.0f + __expf(-h1)));
  o.z = f2b(h2 / (1.0f + __expf(-h2)));
  o.w = f2b(h3 / (1.0f + __expf(-h3)));
  *(ushort4*)(out + (size_t)row * 1024 + i0) = o;
}

// ---------------------------------------------------------------------------
// Split-K emb projection: embo[b][j] += sum_{i in split} silu(emb[b][i])*We[i][j]
// grid (8, 4, 8): j-block (256 cols), b, i-split (128 rows). embo pre-zeroed
// by transpose4_k; split 0 adds the bias. 256 blocks -> latency hidden.
// ---------------------------------------------------------------------------
__global__ __launch_bounds__(256) void emb_k(const float* __restrict__ emb,
                                             const float* __restrict__ We,
                                             const float* __restrict__ be,
                                             float* __restrict__ embo) {
  int b = blockIdx.y, tid = threadIdx.x;
  int j = blockIdx.x * 256 + tid;
  int i0 = blockIdx.z * 128;
  __shared__ float se[128];
  if (tid < 128) {
    float v = emb[b * 1024 + i0 + tid];
    se[tid] = v / (1.0f + __expf(-v));
  }
  __syncthreads();
  float acc = (blockIdx.z == 0) ? be[j] : 0.f;
#pragma unroll 8
  for (int i = 0; i < 128; ++i) acc += se[i] * We[(size_t)(i0 + i) * 2048 + j];
  atomicAdd(&embo[b * 2048 + j], acc);
}

// ---------------------------------------------------------------------------
// GEMM  C[M][Nn] = A[M][K] @ Bt[Nn][K]^T + bias(f32), A/Bt bf16.
// 128x128 tile, m97 structure. Kept for the small K/V projections.
// mode 0: Cb[row*Nn+col] (bf16)
// mode 1: V-transpose store: Cb[((row>>8)*1024 + col)*256 + (row&255)] (bf16)
// mode 2: Cf[row*Nn+col] = acc + bias + res[row*Nn+col]  (f32 out, f32 res)
// ---------------------------------------------------------------------------
__global__ __launch_bounds__(256) void gemm_bt_k(const u16* __restrict__ A,
                                                 const u16* __restrict__ Bt,
                                                 const float* __restrict__ bias,
                                                 const float* __restrict__ res,
                                                 u16* __restrict__ Cb,
                                                 float* __restrict__ Cf,
                                                 int M, int Nn, int K, int mode) {
  __shared__ __align__(16) short As[128 * 64];
  __shared__ __align__(16) short Bs[128 * 64];
  int tid = threadIdx.x;
  int m0 = blockIdx.x * 128, n0 = blockIdx.y * 128;
  int wave = tid >> 6, lane = tid & 63;
  int l16 = lane & 15, quad = lane >> 4;
  int wm = (wave >> 1) * 64, wn = (wave & 1) * 64;

  f32x4 acc[4][4];
#pragma unroll
  for (int i = 0; i < 4; ++i)
#pragma unroll
    for (int j = 0; j < 4; ++j)
#pragma unroll
      for (int r = 0; r < 4; ++r) acc[i][j][r] = 0.f;

  for (int kt = 0; kt < K; kt += 64) {
#pragma unroll
    for (int p = 0; p < 4; ++p) {
      int c = p * 256 + tid;
      int r = c >> 3;
      int cd = ((c & 7) ^ (r & 7)) * 8;   // swizzled global column (shorts)
      int lb = (p * 256 + wave * 64) * 8; // wave's LDS chunk base (shorts)
      GLOAD_LDS16(A + (size_t)(m0 + r) * K + kt + cd, As + lb);
      GLOAD_LDS16(Bt + (size_t)(n0 + r) * K + kt + cd, Bs + lb);
    }
    __syncthreads();
#pragma unroll
    for (int ks = 0; ks < 2; ++ks) {
      int swz = ((ks * 4 + quad) ^ (l16 & 7)) * 8;
      bf16x8 af[4], bfr[4];
#pragma unroll
      for (int i = 0; i < 4; ++i)
        af[i] = *(const bf16x8*)&As[(wm + i * 16 + l16) * 64 + swz];
#pragma unroll
      for (int j = 0; j < 4; ++j)
        bfr[j] = *(const bf16x8*)&Bs[(wn + j * 16 + l16) * 64 + swz];
#pragma unroll
      for (int i = 0; i < 4; ++i)
#pragma unroll
        for (int j = 0; j < 4; ++j)
          acc[i][j] = __builtin_amdgcn_mfma_f32_16x16x32_bf16(af[i], bfr[j], acc[i][j], 0, 0, 0);
    }
    __syncthreads();
  }

#pragma unroll
  for (int j = 0; j < 4; ++j) {
    int col = n0 + wn + j * 16 + l16;
    float bv = bias[col];
#pragma unroll
    for (int i = 0; i < 4; ++i) {
      int row0 = m0 + wm + i * 16 + quad * 4;
#pragma unroll
      for (int r = 0; r < 4; ++r) {
        int row = row0 + r;
        float v = acc[i][j][r] + bv;
        if (mode == 2) {
          Cf[(size_t)row * Nn + col] = v + res[(size_t)row * Nn + col];
        } else if (mode == 1) {
          Cb[((size_t)((row >> 8) * 1024 + col)) * 256 + (row & 255)] = f2b(v);
        } else {
          Cb[(size_t)row * Nn + col] = f2b(v);
        }
      }
    }
  }
}

// ---------------------------------------------------------------------------
// 256x256-tile deep-pipelined GEMM for the two big 16384x1024x1024 GEMMs.
// BK=32, quad-buffered LDS, 8 waves, counted vmcnt(8), depth-3 prefetch,
// one barrier per tile; coalesced LDS-transpose epilogue.
// ---------------------------------------------------------------------------
__global__ __launch_bounds__(512, 2) void gemm256_k(const u16* __restrict__ A,
                                                    const u16* __restrict__ Bt,
                                                    const float* __restrict__ bias,
                                                    const float* __restrict__ res,
                                                    u16* __restrict__ Cb,
                                                    float* __restrict__ Cf,
                                                    int M, int Nn, int K, int mode) {
  __shared__ __align__(16) short smem[2][4][256 * 32];  // [A/B][buf][tile]
  int tid = threadIdx.x;
  int m0 = blockIdx.x * 256, n0 = blockIdx.y * 256;
  int wave = tid >> 6, lane = tid & 63;
  int l16 = lane & 15, quad = lane >> 4;
  int wm = (wave >> 2) * 128;  // 2 row-wave groups
  int wn = (wave & 3) * 64;    // 4 col-wave groups

  size_t offA[2], offB[2];
  int ldsOff[2];
#pragma unroll
  for (int p = 0; p < 2; ++p) {
    int c = p * 512 + tid;
    int r = c >> 2;
    int cg = (c & 3) ^ ((r >> 1) & 3);
    offA[p] = (size_t)(m0 + r) * K + cg * 8;
    offB[p] = (size_t)(n0 + r) * K + cg * 8;
    ldsOff[p] = (p * 512 + wave * 64) * 8;
  }

  int aoff[8], boff[4];
#pragma unroll
  for (int mi = 0; mi < 8; ++mi) {
    int R = wm + mi * 16 + l16;
    aoff[mi] = R * 32 + ((quad ^ ((R >> 1) & 3)) * 8);
  }
#pragma unroll
  for (int ni = 0; ni < 4; ++ni) {
    int R = wn + ni * 16 + l16;
    boff[ni] = R * 32 + ((quad ^ ((R >> 1) & 3)) * 8);
  }

  f32x4 acc[8][4];
#pragma unroll
  for (int i = 0; i < 8; ++i)
#pragma unroll
    for (int j = 0; j < 4; ++j)
#pragma unroll
      for (int r = 0; r < 4; ++r) acc[i][j][r] = 0.f;

#define STAGE(tt, bufc)                                                        \
  do {                                                                         \
    int kt_ = (tt) * 32;                                                       \
    GLOAD_LDS16(A + offA[0] + kt_, &smem[0][bufc][0] + ldsOff[0]);             \
    GLOAD_LDS16(A + offA[1] + kt_, &smem[0][bufc][0] + ldsOff[1]);             \
    GLOAD_LDS16(Bt + offB[0] + kt_, &smem[1][bufc][0] + ldsOff[0]);            \
    GLOAD_LDS16(Bt + offB[1] + kt_, &smem[1][bufc][0] + ldsOff[1]);            \
  } while (0)

#define TILE(tc, bufc, WAITN, DOSTAGE)                                         \
  do {                                                                         \
    asm volatile("s_waitcnt vmcnt(" #WAITN ")" ::: "memory");                  \
    __builtin_amdgcn_s_barrier();                                              \
    asm volatile("" ::: "memory");                                             \
    if (DOSTAGE) STAGE((tc) + 3, ((bufc) + 3) & 3);                            \
    bf16x8 af[8], bfv[4];                                                      \
    _Pragma("unroll") for (int mi = 0; mi < 8; ++mi)                           \
        af[mi] = *(const bf16x8*)&smem[0][bufc][aoff[mi]];                     \
    _Pragma("unroll") for (int ni = 0; ni < 4; ++ni)                           \
        bfv[ni] = *(const bf16x8*)&smem[1][bufc][boff[ni]];                    \
    __builtin_amdgcn_s_setprio(1);                                             \
    _Pragma("unroll") for (int mi = 0; mi < 8; ++mi)                           \
      _Pragma("unroll") for (int ni = 0; ni < 4; ++ni)                         \
        acc[mi][ni] = __builtin_amdgcn_mfma_f32_16x16x32_bf16(                 \
            af[mi], bfv[ni], acc[mi][ni], 0, 0, 0);                            \
    __builtin_amdgcn_s_setprio(0);                                             \
  } while (0)

  const int NT = K >> 5;  // 32 for K=1024
  STAGE(0, 0);
  STAGE(1, 1);
  STAGE(2, 2);

  int t4 = 0;
  for (; t4 + 8 <= NT; t4 += 4) {
    TILE(t4 + 0, 0, 8, 1);
    TILE(t4 + 1, 1, 8, 1);
    TILE(t4 + 2, 2, 8, 1);
    TILE(t4 + 3, 3, 8, 1);
  }
  TILE(t4 + 0, 0, 8, 1);  // stages tile NT-1
  TILE(t4 + 1, 1, 8, 0);
  TILE(t4 + 2, 2, 4, 0);
  TILE(t4 + 3, 3, 0, 0);
#undef TILE
#undef STAGE

  // coalesced epilogue via LDS transpose (f32[128][256] view, 2 halves)
  float* eps = (float*)&smem[0][0][0];
  float bv[4];
#pragma unroll
  for (int ni = 0; ni < 4; ++ni) bv[ni] = bias[n0 + wn + ni * 16 + l16];

#pragma unroll
  for (int half = 0; half < 2; ++half) {
    __syncthreads();
    if ((wave >> 2) == half) {
#pragma unroll
      for (int mi = 0; mi < 8; ++mi) {
#pragma unroll
        for (int ni = 0; ni < 4; ++ni) {
          int col = wn + ni * 16 + l16;
#pragma unroll
          for (int r = 0; r < 4; ++r) {
            int row = mi * 16 + quad * 4 + r;
            eps[row * 256 + (col ^ (((row >> 2) & 3) << 3))] =
                acc[mi][ni][r] + bv[ni];
          }
        }
      }
    }
    __syncthreads();
#pragma unroll
    for (int p = 0; p < 16; ++p) {
      int row = wave * 16 + p;
      int grow = m0 + half * 128 + row;
      int colb = (lane * 4) ^ (((row >> 2) & 3) << 3);
      f32x4 v = *(const f32x4*)&eps[row * 256 + colb];
      if (mode == 2) {
        float4 rv = ((const float4*)&res[(size_t)grow * Nn + n0])[lane];
        float4 o;
        o.x = v[0] + rv.x; o.y = v[1] + rv.y;
        o.z = v[2] + rv.z; o.w = v[3] + rv.w;
        ((float4*)&Cf[(size_t)grow * Nn + n0])[lane] = o;
      } else {
        ushort4 o;
        o.x = f2b(v[0]); o.y = f2b(v[1]); o.z = f2b(v[2]); o.w = f2b(v[3]);
        ((ushort4*)&Cb[(size_t)grow * Nn + n0])[lane] = o;
      }
    }
  }
}

// ---------------------------------------------------------------------------
// Cross-attention: per (b,h), 64 Q-rows per block (4 waves x 16 rows).
// SWAPPED QK^T (mfma(K,Q)): lane owns Q-row (wb+l16); tokens {16mt+4quad+r}
// in sa[mt][r]. Softmax fully in-register (2 shfl_xor); P->bf16 via
// v_cvt_pk_bf16_f32; P stored with 16 ds_write_b64 (chunk-XOR swizzle
// identical to the PV read). Normalization deferred to post-PV scale.
// ---------------------------------------------------------------------------
__global__ __launch_bounds__(256) void attn_k(const u16* __restrict__ Q,
                                              const u16* __restrict__ Kt,
                                              const u16* __restrict__ VT,
                                              u16* __restrict__ Y) {
  __shared__ __align__(16) short KsPs[256 * 64];  // K tile; reused as P (64x256)
  __shared__ __align__(16) short Vt[64 * 256];    // V^T tile: [d][token]
  int tid = threadIdx.x;
  int t0 = blockIdx.x * 64, h = blockIdx.y, b = blockIdx.z;
  int wave = tid >> 6, lane = tid & 63;
  int l16 = lane & 15, quad = lane >> 4;
  int wb = wave * 16;

#pragma unroll
  for (int p = 0; p < 8; ++p) {
    int c = tid + p * 256;
    int n = c >> 3, cd = c & 7;
    *(int4*)&KsPs[n * 64 + ((cd ^ (n & 7)) * 8)] =
        *(const int4*)(Kt + ((size_t)(b * 256 + n)) * 1024 + h * 64 + cd * 8);
  }
#pragma unroll
  for (int p = 0; p < 8; ++p) {
    int c = tid + p * 256;
    int d = c >> 5, ch = c & 31;
    *(int4*)&Vt[d * 256 + ((ch ^ (d & 7)) * 8)] =
        *(const int4*)(VT + ((size_t)(b * 1024 + h * 64 + d)) * 256 + ch * 8);
  }
  const u16* qrow = Q + ((size_t)(b * 4096 + t0 + wb + l16)) * 1024 + h * 64;
  bf16x8 qf0 = *(const bf16x8*)(qrow + quad * 8);
  bf16x8 qf1 = *(const bf16x8*)(qrow + 32 + quad * 8);
  __syncthreads();

  // swapped QK^T: sa[mt][r] = S[token=16mt+4quad+r][qrow=wb+l16]
  f32x4 sa[16];
#pragma unroll
  for (int mt = 0; mt < 16; ++mt)
#pragma unroll
    for (int r = 0; r < 4; ++r) sa[mt][r] = 0.f;
#pragma unroll
  for (int ks = 0; ks < 2; ++ks) {
    bf16x8 qb = ks ? qf1 : qf0;
#pragma unroll
    for (int mt = 0; mt < 16; ++mt) {
      int n = mt * 16 + l16;
      bf16x8 kf = *(const bf16x8*)&KsPs[n * 64 + (((ks * 4 + quad) ^ (n & 7)) * 8)];
      sa[mt] = __builtin_amdgcn_mfma_f32_16x16x32_bf16(kf, qb, sa[mt], 0, 0, 0);
    }
  }
  __syncthreads();  // all waves done reading K before P overwrites it

  // in-register softmax: lane's 64 tokens + cross-quad combine (lane^16,^32)
  const float CLG = 0.18033688011112042f;  // 0.125 * log2(e)
  float mx = -3.0e38f;
#pragma unroll
  for (int mt = 0; mt < 16; ++mt)
#pragma unroll
    for (int r = 0; r < 4; ++r) mx = fmaxf(mx, sa[mt][r]);
  mx = fmaxf(mx, __shfl_xor(mx, 16));
  mx = fmaxf(mx, __shfl_xor(mx, 32));
  float mxc = mx * CLG;
  float sum = 0.f;
#pragma unroll
  for (int mt = 0; mt < 16; ++mt)
#pragma unroll
    for (int r = 0; r < 4; ++r) {
      float e = __builtin_exp2f(sa[mt][r] * CLG - mxc);
      sa[mt][r] = e;
      sum += e;
    }
  sum += __shfl_xor(sum, 16);
  sum += __shfl_xor(sum, 32);
  float rsc = 1.0f / sum;

  // pack + vector store: row wb+l16; tokens 16mt+4quad+r -> chunk 2mt+(quad>>1),
  // stored at (chunk ^ (row&7)); in-chunk offset (quad&1)*4 + r.
  {
    int prow = wb + l16;
    short* pb = &KsPs[prow * 256 + (quad & 1) * 4];
    int q2 = quad >> 1, swz = l16 & 7;
#pragma unroll
    for (int mt = 0; mt < 16; ++mt) {
      float a0 = sa[mt][0], a1 = sa[mt][1], a2 = sa[mt][2], a3 = sa[mt][3];
      unsigned plo, phi;
      asm("v_cvt_pk_bf16_f32 %0, %1, %2" : "=v"(plo) : "v"(a0), "v"(a1));
      asm("v_cvt_pk_bf16_f32 %0, %1, %2" : "=v"(phi) : "v"(a2), "v"(a3));
      uint2 pk; pk.x = plo; pk.y = phi;
      *(uint2*)(pb + (((2 * mt + q2) ^ swz) * 8)) = pk;
    }
  }
  __syncthreads();

  f32x4 ya[4];
#pragma unroll
  for (int j = 0; j < 4; ++j)
#pragma unroll
    for (int r = 0; r < 4; ++r) ya[j][r] = 0.f;
  int m = wb + l16;
#pragma unroll
  for (int kk = 0; kk < 8; ++kk) {
    bf16x8 af = *(const bf16x8*)&KsPs[m * 256 + (((kk * 4 + quad) ^ (m & 7)) * 8)];
#pragma unroll
    for (int j = 0; j < 4; ++j) {
      int d = j * 16 + l16;
      bf16x8 bfr = *(const bf16x8*)&Vt[d * 256 + (((kk * 4 + quad) ^ (d & 7)) * 8)];
      ya[j] = __builtin_amdgcn_mfma_f32_16x16x32_bf16(af, bfr, ya[j], 0, 0, 0);
    }
  }
  // per-output-row 1/sum: row quad*4+r's rsc lives in lanes with l16=quad*4+r
  float rscv[4];
#pragma unroll
  for (int r = 0; r < 4; ++r) rscv[r] = __shfl(rsc, quad * 4 + r);
#pragma unroll
  for (int j = 0; j < 4; ++j)
#pragma unroll
    for (int r = 0; r < 4; ++r)
      Y[((size_t)(b * 4096 + t0 + wb + quad * 4 + r)) * 1024 + h * 64 + j * 16 + l16] =
          f2b(ya[j][r] * rscv[r]);
}

// ---------------------------------------------------------------------------
extern "C" void kernel_launch(void* const* d_in, const int* in_sizes, int n_in,
                              void* d_out, int out_size, void* d_ws, size_t ws_size,
                              hipStream_t stream) {
  const float* x       = (const float*)d_in[0];
  const float* xf      = (const float*)d_in[1];
  const float* emb     = (const float*)d_in[2];
  const float* norm_g  = (const float*)d_in[3];
  const float* norm_b  = (const float*)d_in[4];
  const float* tnorm_g = (const float*)d_in[5];
  const float* tnorm_b = (const float*)d_in[6];
  const float* Wq      = (const float*)d_in[7];
  const float* bq      = (const float*)d_in[8];
  const float* Wk      = (const float*)d_in[9];
  const float* bk      = (const float*)d_in[10];
  const float* Wv      = (const float*)d_in[11];
  const float* bv      = (const float*)d_in[12];
  const float* We      = (const float*)d_in[13];
  const float* be      = (const float*)d_in[14];
  const float* snorm_g = (const float*)d_in[15];
  const float* snorm_b = (const float*)d_in[16];
  const float* Wo      = (const float*)d_in[17];
  const float* bo      = (const float*)d_in[18];

  const size_t MB = 1024 * 1024;
  char* dout = (char*)d_out;
  u16* qbuf = (u16*)(dout);             // 32 MB bf16 Q (dead after attn)
  u16* wqt  = (u16*)(dout + 32 * MB);   // 2 MB   (dead after Q-GEMM)
  u16* wkt  = (u16*)(dout + 34 * MB);   // 1.5 MB (dead after K-GEMM)
  u16* wvt  = (u16*)(dout + 36 * MB);   // 1.5 MB (dead after V-GEMM)
  float* out = (float*)d_out;

  char* ws = (char*)d_ws;
  u16* big1 = (u16*)(ws);                        // 32 MB: LN(x) -> y -> s
  u16* xfn  = (u16*)(ws + 32 * MB);              // 1.5 MB
  u16* kws  = (u16*)(ws + 33 * MB + 512 * 1024); // 2 MB  (B,256,1024)
  u16* vtws = (u16*)(ws + 35 * MB + 512 * 1024); // 2 MB  (B,1024,256)
  u16* wot  = (u16*)(ws + 37 * MB + 512 * 1024); // 2 MB  (needed during final GEMM)
  float* embo = (float*)(ws + 39 * MB + 512 * 1024); // 32 KB f32

  transpose4_k<<<dim3(32, 32, 4), dim3(32, 8), 0, stream>>>(
      Wq, Wk, Wv, Wo, wqt, wkt, wvt, wot, embo);

  ln_k<<<16384, 256, 0, stream>>>(x, norm_g, norm_b, big1, 1024);
  ln_k<<<1024, 256, 0, stream>>>(xf, tnorm_g, tnorm_b, xfn, 768);

  gemm256_k<<<dim3(64, 4), 512, 0, stream>>>(big1, wqt, bq, nullptr, qbuf, nullptr, 16384, 1024, 1024, 0);
  gemm_bt_k<<<dim3(8, 8), 256, 0, stream>>>(xfn, wkt, bk, nullptr, kws, nullptr, 1024, 1024, 768, 0);
  gemm_bt_k<<<dim3(8, 8), 256, 0, stream>>>(xfn, wvt, bv, nullptr, vtws, nullptr, 1024, 1024, 768, 1);

  emb_k<<<dim3(8, 4, 8), 256, 0, stream>>>(emb, We, be, embo);

  attn_k<<<dim3(64, 16, 4), 256, 0, stream>>>(qbuf, kws, vtws, big1);

  style_k<<<16384, 256, 0, stream>>>(big1, snorm_g, snorm_b, embo, big1);

  gemm256_k<<<dim3(64, 4), 512, 0, stream>>>(big1, wot, bo, x, nullptr, out, 16384, 1024, 1024, 2);
}

// Round 6
// 371.514 us; speedup vs baseline: 1.3828x; 1.0139x over previous
//
#include <hip/hip_runtime.h>

typedef unsigned short u16;
typedef short bf16x8 __attribute__((ext_vector_type(8)));
typedef float f32x4 __attribute__((ext_vector_type(4)));

// Problem constants: B=4, T=4096, D=1024, N=256, L=768, H=16, dh=64, TE=1024
// I/O dtype: float32 (per reference). Internal MFMA compute: bf16.

__device__ __forceinline__ float b2f(u16 u) {
  union { unsigned int u; float f; } x; x.u = ((unsigned int)u) << 16; return x.f;
}
__device__ __forceinline__ u16 f2b(float f) {
  union { float f; unsigned int u; } x; x.f = f;
  unsigned int u = x.u;
  return (u16)((u + 0x7FFFu + ((u >> 16) & 1u)) >> 16);  // RNE
}

// async global->LDS, 16B per lane. LDS dest = wave-uniform base + lane*16.
#define GLOAD_LDS16(g, l)                                                      \
  __builtin_amdgcn_global_load_lds(                                            \
      (const __attribute__((address_space(1))) unsigned int*)(g),              \
      (__attribute__((address_space(3))) unsigned int*)(l), 16, 0, 0)

// ---------------------------------------------------------------------------
// Fused 4-way transpose + f32->bf16: dst[C][R] = bf16(src[R][C]), C=1024.
// grid (32, 32, 4), block (32,8). z selects {Wq,Wk,Wv,Wo}; R in {1024,768}.
// Also zero-fills embo (8192 f32) so emb_k can atomicAdd split-K partials.
// ---------------------------------------------------------------------------
__global__ __launch_bounds__(256) void transpose4_k(
    const float* __restrict__ Wq, const float* __restrict__ Wk,
    const float* __restrict__ Wv, const float* __restrict__ Wo,
    u16* __restrict__ wqt, u16* __restrict__ wkt,
    u16* __restrict__ wvt, u16* __restrict__ wot,
    float* __restrict__ embo) {
  if (blockIdx.z == 0 && blockIdx.y == 0) {
    int idx = blockIdx.x * 256 + threadIdx.y * 32 + threadIdx.x;
    embo[idx] = 0.f;  // 32 blocks x 256 threads = 8192 = B*2D
  }
  const float* src; u16* dst; int R;
  switch (blockIdx.z) {
    case 0: src = Wq; dst = wqt; R = 1024; break;
    case 1: src = Wk; dst = wkt; R = 768;  break;
    case 2: src = Wv; dst = wvt; R = 768;  break;
    default: src = Wo; dst = wot; R = 1024; break;
  }
  int bx = blockIdx.x * 32, by = blockIdx.y * 32;
  if (by >= R) return;
  __shared__ float t[32][33];
  int x = threadIdx.x, y = threadIdx.y;
#pragma unroll
  for (int i = 0; i < 4; ++i)
    t[y * 4 + i][x] = src[(size_t)(by + y * 4 + i) * 1024 + bx + x];
  __syncthreads();
#pragma unroll
  for (int i = 0; i < 4; ++i)
    dst[(size_t)(bx + y * 4 + i) * R + by + x] = f2b(t[x][y * 4 + i]);
}

// ---------------------------------------------------------------------------
// Row LayerNorm, f32 in -> bf16 out. One block per row. C in {768, 1024}.
// ---------------------------------------------------------------------------
__global__ __launch_bounds__(256) void ln_k(const float* __restrict__ in,
                                            const float* __restrict__ g,
                                            const float* __restrict__ bta,
                                            u16* __restrict__ out, int C) {
  int row = blockIdx.x, tid = threadIdx.x;
  const float* p = in + (size_t)row * C;
  int i0 = tid * 4;
  bool act = i0 < C;
  float v0 = 0.f, v1 = 0.f, v2 = 0.f, v3 = 0.f;
  if (act) {
    float4 u = *(const float4*)(p + i0);
    v0 = u.x; v1 = u.y; v2 = u.z; v3 = u.w;
  }
  float s = v0 + v1 + v2 + v3;
  float q = v0 * v0 + v1 * v1 + v2 * v2 + v3 * v3;
  __shared__ float red[8];
#pragma unroll
  for (int m = 32; m; m >>= 1) { s += __shfl_xor(s, m); q += __shfl_xor(q, m); }
  if ((tid & 63) == 0) { red[tid >> 6] = s; red[4 + (tid >> 6)] = q; }
  __syncthreads();
  s = red[0] + red[1] + red[2] + red[3];
  q = red[4] + red[5] + red[6] + red[7];
  float invC = 1.0f / (float)C;
  float mu = s * invC;
  float rs = rsqrtf(q * invC - mu * mu + 1e-5f);
  if (act) {
    float4 ug = *(const float4*)(g + i0);
    float4 ub = *(const float4*)(bta + i0);
    ushort4 o;
    o.x = f2b((v0 - mu) * rs * ug.x + ub.x);
    o.y = f2b((v1 - mu) * rs * ug.y + ub.y);
    o.z = f2b((v2 - mu) * rs * ug.z + ub.z);
    o.w = f2b((v3 - mu) * rs * ug.w + ub.w);
    *(ushort4*)(out + (size_t)row * C + i0) = o;
  }
}

// ---------------------------------------------------------------------------
// Stylization (in-place safe): out = bf16( silu( LN(y)*(1+scale_b) + shift_b ) ).
// ---------------------------------------------------------------------------
__global__ __launch_bounds__(256) void style_k(const u16* __restrict__ y,
                                               const float* __restrict__ g,
                                               const float* __restrict__ bta,
                                               const float* __restrict__ embo,
                                               u16* __restrict__ out) {
  int row = blockIdx.x, tid = threadIdx.x;
  int b = row >> 12;  // T=4096
  const u16* p = y + (size_t)row * 1024;
  int i0 = tid * 4;
  ushort4 u = *(const ushort4*)(p + i0);
  float v0 = b2f(u.x), v1 = b2f(u.y), v2 = b2f(u.z), v3 = b2f(u.w);
  float s = v0 + v1 + v2 + v3;
  float q = v0 * v0 + v1 * v1 + v2 * v2 + v3 * v3;
  __shared__ float red[8];
#pragma unroll
  for (int m = 32; m; m >>= 1) { s += __shfl_xor(s, m); q += __shfl_xor(q, m); }
  if ((tid & 63) == 0) { red[tid >> 6] = s; red[4 + (tid >> 6)] = q; }
  __syncthreads();
  s = red[0] + red[1] + red[2] + red[3];
  q = red[4] + red[5] + red[6] + red[7];
  const float invC = 1.0f / 1024.0f;
  float mu = s * invC;
  float rs = rsqrtf(q * invC - mu * mu + 1e-5f);
  float4 ug = *(const float4*)(g + i0);
  float4 ub = *(const float4*)(bta + i0);
  float4 sc = *(const float4*)(embo + b * 2048 + i0);
  float4 sh = *(const float4*)(embo + b * 2048 + 1024 + i0);
  float h0 = ((v0 - mu) * rs * ug.x + ub.x) * (1.0f + sc.x) + sh.x;
  float h1 = ((v1 - mu) * rs * ug.y + ub.y) * (1.0f + sc.y) + sh.y;
  float h2 = ((v2 - mu) * rs * ug.z + ub.z) * (1.0f + sc.z) + sh.z;
  float h3 = ((v3 - mu) * rs * ug.w + ub.w) * (1.0f + sc.w) + sh.w;
  ushort4 o;
  o.x = f2b(h0 / (1.0f + __expf(-h0)));
  o.y = f2b(h1 / (1.0f + __expf(-h1)));
  o.z = f2b(h2 / (1.0f + __expf(-h2)));
  o.w = f2b(h3 / (1.0f + __expf(-h3)));
  *(ushort4*)(out + (size_t)row * 1024 + i0) = o;
}

// ---------------------------------------------------------------------------
// Split-K emb projection: embo[b][j] += sum_{i in split} silu(emb[b][i])*We[i][j]
// grid (8, 4, 8). embo pre-zeroed by transpose4_k; split 0 adds the bias.
// ---------------------------------------------------------------------------
__global__ __launch_bounds__(256) void emb_k(const float* __restrict__ emb,
                                             const float* __restrict__ We,
                                             const float* __restrict__ be,
                                             float* __restrict__ embo) {
  int b = blockIdx.y, tid = threadIdx.x;
  int j = blockIdx.x * 256 + tid;
  int i0 = blockIdx.z * 128;
  __shared__ float se[128];
  if (tid < 128) {
    float v = emb[b * 1024 + i0 + tid];
    se[tid] = v / (1.0f + __expf(-v));
  }
  __syncthreads();
  float acc = (blockIdx.z == 0) ? be[j] : 0.f;
#pragma unroll 8
  for (int i = 0; i < 128; ++i) acc += se[i] * We[(size_t)(i0 + i) * 2048 + j];
  atomicAdd(&embo[b * 2048 + j], acc);
}

// ---------------------------------------------------------------------------
// GEMM  C[M][Nn] = A[M][K] @ Bt[Nn][K]^T + bias(f32), A/Bt bf16.
// 128x128 tile, m97 structure. Kept for the small K/V projections.
// mode 0: Cb[row*Nn+col] (bf16)
// mode 1: V-transpose store: Cb[((row>>8)*1024 + col)*256 + (row&255)] (bf16)
// mode 2: Cf[row*Nn+col] = acc + bias + res[row*Nn+col]  (f32 out, f32 res)
// ---------------------------------------------------------------------------
__global__ __launch_bounds__(256) void gemm_bt_k(const u16* __restrict__ A,
                                                 const u16* __restrict__ Bt,
                                                 const float* __restrict__ bias,
                                                 const float* __restrict__ res,
                                                 u16* __restrict__ Cb,
                                                 float* __restrict__ Cf,
                                                 int M, int Nn, int K, int mode) {
  __shared__ __align__(16) short As[128 * 64];
  __shared__ __align__(16) short Bs[128 * 64];
  int tid = threadIdx.x;
  int m0 = blockIdx.x * 128, n0 = blockIdx.y * 128;
  int wave = tid >> 6, lane = tid & 63;
  int l16 = lane & 15, quad = lane >> 4;
  int wm = (wave >> 1) * 64, wn = (wave & 1) * 64;

  f32x4 acc[4][4];
#pragma unroll
  for (int i = 0; i < 4; ++i)
#pragma unroll
    for (int j = 0; j < 4; ++j)
#pragma unroll
      for (int r = 0; r < 4; ++r) acc[i][j][r] = 0.f;

  for (int kt = 0; kt < K; kt += 64) {
#pragma unroll
    for (int p = 0; p < 4; ++p) {
      int c = p * 256 + tid;
      int r = c >> 3;
      int cd = ((c & 7) ^ (r & 7)) * 8;   // swizzled global column (shorts)
      int lb = (p * 256 + wave * 64) * 8; // wave's LDS chunk base (shorts)
      GLOAD_LDS16(A + (size_t)(m0 + r) * K + kt + cd, As + lb);
      GLOAD_LDS16(Bt + (size_t)(n0 + r) * K + kt + cd, Bs + lb);
    }
    __syncthreads();
#pragma unroll
    for (int ks = 0; ks < 2; ++ks) {
      int swz = ((ks * 4 + quad) ^ (l16 & 7)) * 8;
      bf16x8 af[4], bfr[4];
#pragma unroll
      for (int i = 0; i < 4; ++i)
        af[i] = *(const bf16x8*)&As[(wm + i * 16 + l16) * 64 + swz];
#pragma unroll
      for (int j = 0; j < 4; ++j)
        bfr[j] = *(const bf16x8*)&Bs[(wn + j * 16 + l16) * 64 + swz];
#pragma unroll
      for (int i = 0; i < 4; ++i)
#pragma unroll
        for (int j = 0; j < 4; ++j)
          acc[i][j] = __builtin_amdgcn_mfma_f32_16x16x32_bf16(af[i], bfr[j], acc[i][j], 0, 0, 0);
    }
    __syncthreads();
  }

#pragma unroll
  for (int j = 0; j < 4; ++j) {
    int col = n0 + wn + j * 16 + l16;
    float bv = bias[col];
#pragma unroll
    for (int i = 0; i < 4; ++i) {
      int row0 = m0 + wm + i * 16 + quad * 4;
#pragma unroll
      for (int r = 0; r < 4; ++r) {
        int row = row0 + r;
        float v = acc[i][j][r] + bv;
        if (mode == 2) {
          Cf[(size_t)row * Nn + col] = v + res[(size_t)row * Nn + col];
        } else if (mode == 1) {
          Cb[((size_t)((row >> 8) * 1024 + col)) * 256 + (row & 255)] = f2b(v);
        } else {
          Cb[(size_t)row * Nn + col] = f2b(v);
        }
      }
    }
  }
}

// ---------------------------------------------------------------------------
// 128x256-tile deep-pipelined GEMM, 2 BLOCKS/CU, for the two big
// 16384x1024x1024 GEMMs. BK=32, TRIPLE-buffered LDS (72 KiB/block), 8 waves
// (2M x 4N), per-wave output 64x64 (acc[4][4]).
// Per K-tile t: s_waitcnt vmcnt(3) [t's 3 loads landed; t+1's in flight];
// s_barrier; stage t+2 into buf (t+2)%3 [its last readers were tile t-1,
// all retired at this barrier]; 8 ds_read_b128; 16 MFMA (setprio 1).
// Counted vmcnt hits 0 only at the final tile. ONE barrier per tile.
// Depth-2 prefetch: tile t's loads issued 2 tile-times ahead.
// grid (M/128, Nn/256) = (128,4) = 512 blocks -> 2 blocks/CU: cross-block
// overlap hides each block's barrier/vmcnt convoy (m97 insight; the 1-block/CU
// 256^2 variant measured 5000 cyc/BK32-tile vs 1650 for multi-block).
// Bank swizzle: LDS slot (r, s) holds global chunk (r, s^((r>>1)&3)).
// Epilogue: coalesced LDS-transpose in 64-row f32[64][256] chunks.
// mode 0: Cb = bf16(acc+bias);  mode 2: Cf = acc+bias+res (f32).
// ---------------------------------------------------------------------------
__global__ __launch_bounds__(512, 4) void gemm256_k(const u16* __restrict__ A,
                                                    const u16* __restrict__ Bt,
                                                    const float* __restrict__ bias,
                                                    const float* __restrict__ res,
                                                    u16* __restrict__ Cb,
                                                    float* __restrict__ Cf,
                                                    int M, int Nn, int K, int mode) {
  __shared__ __align__(16) short smem[36864];  // 72 KiB: [A0 A1 A2 | B0 B1 B2]
  short* AsB = smem;            // 3 x 4096 shorts (128x32 each)
  short* BsB = smem + 12288;    // 3 x 8192 shorts (256x32 each)
  int tid = threadIdx.x;
  int m0 = blockIdx.x * 128, n0 = blockIdx.y * 256;
  int wave = tid >> 6, lane = tid & 63;
  int l16 = lane & 15, quad = lane >> 4;
  int wm = (wave >> 2) * 64;   // 2 row-wave groups
  int wn = (wave & 3) * 64;    // 4 col-wave groups

  // Staging source offsets (shorts). Chunk c -> LDS slot (r=c>>2, s=c&3)
  // <- global chunk (r, s ^ ((r>>1)&3)).
  size_t offA;
  {
    int r = tid >> 2;
    int cg = (tid & 3) ^ ((r >> 1) & 3);
    offA = (size_t)(m0 + r) * K + cg * 8;
  }
  int ldsA = tid * 8;  // wave-uniform base + lane*16B
  size_t offB[2];
  int ldsB[2];
#pragma unroll
  for (int p = 0; p < 2; ++p) {
    int c = p * 512 + tid;
    int r = c >> 2;
    int cg = (c & 3) ^ ((r >> 1) & 3);
    offB[p] = (size_t)(n0 + r) * K + cg * 8;
    ldsB[p] = c * 8;
  }

  // Fragment read offsets (shorts): row R, k-chunk quad.
  int aoff[4], boff[4];
#pragma unroll
  for (int mi = 0; mi < 4; ++mi) {
    int R = wm + mi * 16 + l16;
    aoff[mi] = R * 32 + ((quad ^ ((R >> 1) & 3)) * 8);
  }
#pragma unroll
  for (int ni = 0; ni < 4; ++ni) {
    int R = wn + ni * 16 + l16;
    boff[ni] = R * 32 + ((quad ^ ((R >> 1) & 3)) * 8);
  }

  f32x4 acc[4][4];
#pragma unroll
  for (int i = 0; i < 4; ++i)
#pragma unroll
    for (int j = 0; j < 4; ++j)
#pragma unroll
      for (int r = 0; r < 4; ++r) acc[i][j][r] = 0.f;

#define STAGE(tt, bufc)                                                        \
  do {                                                                         \
    int kt_ = (tt) * 32;                                                       \
    GLOAD_LDS16(A + offA + kt_, AsB + (bufc) * 4096 + ldsA);                   \
    GLOAD_LDS16(Bt + offB[0] + kt_, BsB + (bufc) * 8192 + ldsB[0]);            \
    GLOAD_LDS16(Bt + offB[1] + kt_, BsB + (bufc) * 8192 + ldsB[1]);            \
  } while (0)

#define COMPUTE(curc)                                                          \
  do {                                                                         \
    const short* as_ = AsB + (curc) * 4096;                                    \
    const short* bs_ = BsB + (curc) * 8192;                                    \
    bf16x8 af[4], bfv[4];                                                      \
    _Pragma("unroll") for (int mi = 0; mi < 4; ++mi)                           \
        af[mi] = *(const bf16x8*)&as_[aoff[mi]];                               \
    _Pragma("unroll") for (int ni = 0; ni < 4; ++ni)                           \
        bfv[ni] = *(const bf16x8*)&bs_[boff[ni]];                              \
    __builtin_amdgcn_s_setprio(1);                                             \
    _Pragma("unroll") for (int mi = 0; mi < 4; ++mi)                           \
      _Pragma("unroll") for (int ni = 0; ni < 4; ++ni)                         \
        acc[mi][ni] = __builtin_amdgcn_mfma_f32_16x16x32_bf16(                 \
            af[mi], bfv[ni], acc[mi][ni], 0, 0, 0);                            \
    __builtin_amdgcn_s_setprio(0);                                             \
  } while (0)

  const int NT = K >> 5;  // 32 for K=1024
  // prologue: stage tiles 0,1 (6 loads in flight)
  STAGE(0, 0);
  STAGE(1, 1);

  int cur = 0;
  for (int t = 0; t < NT - 1; ++t) {
    asm volatile("s_waitcnt vmcnt(3)" ::: "memory");  // tile t landed
    __builtin_amdgcn_s_barrier();
    asm volatile("" ::: "memory");
    if (t + 2 < NT) {
      int nb = cur + 2; if (nb >= 3) nb -= 3;
      STAGE(t + 2, nb);  // overwrites tile t-1's buffer: readers done
    }
    COMPUTE(cur);
    cur = (cur == 2) ? 0 : cur + 1;
  }
  // final tile: drain (only point where vmcnt reaches 0)
  asm volatile("s_waitcnt vmcnt(0)" ::: "memory");
  __builtin_amdgcn_s_barrier();
  asm volatile("" ::: "memory");
  COMPUTE(cur);
#undef COMPUTE
#undef STAGE

  // ---- coalesced epilogue via LDS transpose, 64-row chunks ---------------
  // eps = f32[64][256] view (64 KiB of the 72 KiB staging LDS).
  float* eps = (float*)smem;
  float bv[4];
#pragma unroll
  for (int ni = 0; ni < 4; ++ni) bv[ni] = bias[n0 + wn + ni * 16 + l16];

#pragma unroll
  for (int half = 0; half < 2; ++half) {
    __syncthreads();  // prior LDS reads (main loop / prev chunk) done
    if ((wave >> 2) == half) {
#pragma unroll
      for (int mi = 0; mi < 4; ++mi) {
#pragma unroll
        for (int ni = 0; ni < 4; ++ni) {
          int col = wn + ni * 16 + l16;
#pragma unroll
          for (int r = 0; r < 4; ++r) {
            int row = mi * 16 + quad * 4 + r;
            eps[row * 256 + (col ^ (((row >> 2) & 3) << 3))] =
                acc[mi][ni][r] + bv[ni];
          }
        }
      }
    }
    __syncthreads();
#pragma unroll
    for (int p = 0; p < 8; ++p) {
      int row = wave * 8 + p;
      int grow = m0 + half * 64 + row;
      int colb = (lane * 4) ^ (((row >> 2) & 3) << 3);
      f32x4 v = *(const f32x4*)&eps[row * 256 + colb];
      if (mode == 2) {
        float4 rv = ((const float4*)&res[(size_t)grow * Nn + n0])[lane];
        float4 o;
        o.x = v[0] + rv.x; o.y = v[1] + rv.y;
        o.z = v[2] + rv.z; o.w = v[3] + rv.w;
        ((float4*)&Cf[(size_t)grow * Nn + n0])[lane] = o;
      } else {
        ushort4 o;
        o.x = f2b(v[0]); o.y = f2b(v[1]); o.z = f2b(v[2]); o.w = f2b(v[3]);
        ((ushort4*)&Cb[(size_t)grow * Nn + n0])[lane] = o;
      }
    }
  }
}

// ---------------------------------------------------------------------------
// Cross-attention: per (b,h), 64 Q-rows per block (4 waves x 16 rows).
// SWAPPED QK^T (mfma(K,Q)): lane owns Q-row (wb+l16); tokens {16mt+4quad+r}
// in sa[mt][r]. Softmax fully in-register (2 shfl_xor); P->bf16 via
// v_cvt_pk_bf16_f32; P stored with 16 ds_write_b64 (chunk-XOR swizzle
// identical to the PV read). Normalization deferred to post-PV scale.
// ---------------------------------------------------------------------------
__global__ __launch_bounds__(256) void attn_k(const u16* __restrict__ Q,
                                              const u16* __restrict__ Kt,
                                              const u16* __restrict__ VT,
                                              u16* __restrict__ Y) {
  __shared__ __align__(16) short KsPs[256 * 64];  // K tile; reused as P (64x256)
  __shared__ __align__(16) short Vt[64 * 256];    // V^T tile: [d][token]
  int tid = threadIdx.x;
  int t0 = blockIdx.x * 64, h = blockIdx.y, b = blockIdx.z;
  int wave = tid >> 6, lane = tid & 63;
  int l16 = lane & 15, quad = lane >> 4;
  int wb = wave * 16;

#pragma unroll
  for (int p = 0; p < 8; ++p) {
    int c = tid + p * 256;
    int n = c >> 3, cd = c & 7;
    *(int4*)&KsPs[n * 64 + ((cd ^ (n & 7)) * 8)] =
        *(const int4*)(Kt + ((size_t)(b * 256 + n)) * 1024 + h * 64 + cd * 8);
  }
#pragma unroll
  for (int p = 0; p < 8; ++p) {
    int c = tid + p * 256;
    int d = c >> 5, ch = c & 31;
    *(int4*)&Vt[d * 256 + ((ch ^ (d & 7)) * 8)] =
        *(const int4*)(VT + ((size_t)(b * 1024 + h * 64 + d)) * 256 + ch * 8);
  }
  const u16* qrow = Q + ((size_t)(b * 4096 + t0 + wb + l16)) * 1024 + h * 64;
  bf16x8 qf0 = *(const bf16x8*)(qrow + quad * 8);
  bf16x8 qf1 = *(const bf16x8*)(qrow + 32 + quad * 8);
  __syncthreads();

  // swapped QK^T: sa[mt][r] = S[token=16mt+4quad+r][qrow=wb+l16]
  f32x4 sa[16];
#pragma unroll
  for (int mt = 0; mt < 16; ++mt)
#pragma unroll
    for (int r = 0; r < 4; ++r) sa[mt][r] = 0.f;
#pragma unroll
  for (int ks = 0; ks < 2; ++ks) {
    bf16x8 qb = ks ? qf1 : qf0;
#pragma unroll
    for (int mt = 0; mt < 16; ++mt) {
      int n = mt * 16 + l16;
      bf16x8 kf = *(const bf16x8*)&KsPs[n * 64 + (((ks * 4 + quad) ^ (n & 7)) * 8)];
      sa[mt] = __builtin_amdgcn_mfma_f32_16x16x32_bf16(kf, qb, sa[mt], 0, 0, 0);
    }
  }
  __syncthreads();  // all waves done reading K before P overwrites it

  // in-register softmax: lane's 64 tokens + cross-quad combine (lane^16,^32)
  const float CLG = 0.18033688011112042f;  // 0.125 * log2(e)
  float mx = -3.0e38f;
#pragma unroll
  for (int mt = 0; mt < 16; ++mt)
#pragma unroll
    for (int r = 0; r < 4; ++r) mx = fmaxf(mx, sa[mt][r]);
  mx = fmaxf(mx, __shfl_xor(mx, 16));
  mx = fmaxf(mx, __shfl_xor(mx, 32));
  float mxc = mx * CLG;
  float sum = 0.f;
#pragma unroll
  for (int mt = 0; mt < 16; ++mt)
#pragma unroll
    for (int r = 0; r < 4; ++r) {
      float e = __builtin_exp2f(sa[mt][r] * CLG - mxc);
      sa[mt][r] = e;
      sum += e;
    }
  sum += __shfl_xor(sum, 16);
  sum += __shfl_xor(sum, 32);
  float rsc = 1.0f / sum;

  // pack + vector store: row wb+l16; tokens 16mt+4quad+r -> chunk 2mt+(quad>>1),
  // stored at (chunk ^ (row&7)); in-chunk offset (quad&1)*4 + r.
  {
    int prow = wb + l16;
    short* pb = &KsPs[prow * 256 + (quad & 1) * 4];
    int q2 = quad >> 1, swz = l16 & 7;
#pragma unroll
    for (int mt = 0; mt < 16; ++mt) {
      float a0 = sa[mt][0], a1 = sa[mt][1], a2 = sa[mt][2], a3 = sa[mt][3];
      unsigned plo, phi;
      asm("v_cvt_pk_bf16_f32 %0, %1, %2" : "=v"(plo) : "v"(a0), "v"(a1));
      asm("v_cvt_pk_bf16_f32 %0, %1, %2" : "=v"(phi) : "v"(a2), "v"(a3));
      uint2 pk; pk.x = plo; pk.y = phi;
      *(uint2*)(pb + (((2 * mt + q2) ^ swz) * 8)) = pk;
    }
  }
  __syncthreads();

  f32x4 ya[4];
#pragma unroll
  for (int j = 0; j < 4; ++j)
#pragma unroll
    for (int r = 0; r < 4; ++r) ya[j][r] = 0.f;
  int m = wb + l16;
#pragma unroll
  for (int kk = 0; kk < 8; ++kk) {
    bf16x8 af = *(const bf16x8*)&KsPs[m * 256 + (((kk * 4 + quad) ^ (m & 7)) * 8)];
#pragma unroll
    for (int j = 0; j < 4; ++j) {
      int d = j * 16 + l16;
      bf16x8 bfr = *(const bf16x8*)&Vt[d * 256 + (((kk * 4 + quad) ^ (d & 7)) * 8)];
      ya[j] = __builtin_amdgcn_mfma_f32_16x16x32_bf16(af, bfr, ya[j], 0, 0, 0);
    }
  }
  // per-output-row 1/sum: row quad*4+r's rsc lives in lanes with l16=quad*4+r
  float rscv[4];
#pragma unroll
  for (int r = 0; r < 4; ++r) rscv[r] = __shfl(rsc, quad * 4 + r);
#pragma unroll
  for (int j = 0; j < 4; ++j)
#pragma unroll
    for (int r = 0; r < 4; ++r)
      Y[((size_t)(b * 4096 + t0 + wb + quad * 4 + r)) * 1024 + h * 64 + j * 16 + l16] =
          f2b(ya[j][r] * rscv[r]);
}

// ---------------------------------------------------------------------------
extern "C" void kernel_launch(void* const* d_in, const int* in_sizes, int n_in,
                              void* d_out, int out_size, void* d_ws, size_t ws_size,
                              hipStream_t stream) {
  const float* x       = (const float*)d_in[0];
  const float* xf      = (const float*)d_in[1];
  const float* emb     = (const float*)d_in[2];
  const float* norm_g  = (const float*)d_in[3];
  const float* norm_b  = (const float*)d_in[4];
  const float* tnorm_g = (const float*)d_in[5];
  const float* tnorm_b = (const float*)d_in[6];
  const float* Wq      = (const float*)d_in[7];
  const float* bq      = (const float*)d_in[8];
  const float* Wk      = (const float*)d_in[9];
  const float* bk      = (const float*)d_in[10];
  const float* Wv      = (const float*)d_in[11];
  const float* bv      = (const float*)d_in[12];
  const float* We      = (const float*)d_in[13];
  const float* be      = (const float*)d_in[14];
  const float* snorm_g = (const float*)d_in[15];
  const float* snorm_b = (const float*)d_in[16];
  const float* Wo      = (const float*)d_in[17];
  const float* bo      = (const float*)d_in[18];

  const size_t MB = 1024 * 1024;
  char* dout = (char*)d_out;
  u16* qbuf = (u16*)(dout);             // 32 MB bf16 Q (dead after attn)
  u16* wqt  = (u16*)(dout + 32 * MB);   // 2 MB   (dead after Q-GEMM)
  u16* wkt  = (u16*)(dout + 34 * MB);   // 1.5 MB (dead after K-GEMM)
  u16* wvt  = (u16*)(dout + 36 * MB);   // 1.5 MB (dead after V-GEMM)
  float* out = (float*)d_out;

  char* ws = (char*)d_ws;
  u16* big1 = (u16*)(ws);                        // 32 MB: LN(x) -> y -> s
  u16* xfn  = (u16*)(ws + 32 * MB);              // 1.5 MB
  u16* kws  = (u16*)(ws + 33 * MB + 512 * 1024); // 2 MB  (B,256,1024)
  u16* vtws = (u16*)(ws + 35 * MB + 512 * 1024); // 2 MB  (B,1024,256)
  u16* wot  = (u16*)(ws + 37 * MB + 512 * 1024); // 2 MB  (needed during final GEMM)
  float* embo = (float*)(ws + 39 * MB + 512 * 1024); // 32 KB f32

  transpose4_k<<<dim3(32, 32, 4), dim3(32, 8), 0, stream>>>(
      Wq, Wk, Wv, Wo, wqt, wkt, wvt, wot, embo);

  ln_k<<<16384, 256, 0, stream>>>(x, norm_g, norm_b, big1, 1024);
  ln_k<<<1024, 256, 0, stream>>>(xf, tnorm_g, tnorm_b, xfn, 768);

  gemm256_k<<<dim3(128, 4), 512, 0, stream>>>(big1, wqt, bq, nullptr, qbuf, nullptr, 16384, 1024, 1024, 0);
  gemm_bt_k<<<dim3(8, 8), 256, 0, stream>>>(xfn, wkt, bk, nullptr, kws, nullptr, 1024, 1024, 768, 0);
  gemm_bt_k<<<dim3(8, 8), 256, 0, stream>>>(xfn, wvt, bv, nullptr, vtws, nullptr, 1024, 1024, 768, 1);

  emb_k<<<dim3(8, 4, 8), 256, 0, stream>>>(emb, We, be, embo);

  attn_k<<<dim3(64, 16, 4), 256, 0, stream>>>(qbuf, kws, vtws, big1);

  style_k<<<16384, 256, 0, stream>>>(big1, snorm_g, snorm_b, embo, big1);

  gemm256_k<<<dim3(128, 4), 512, 0, stream>>>(big1, wot, bo, x, nullptr, out, 16384, 1024, 1024, 2);
}